// Round 1
// baseline (545.511 us; speedup 1.0000x reference)
//
#include <hip/hip_runtime.h>

typedef unsigned short u16;
typedef __attribute__((ext_vector_type(8))) __bf16 bf16x8;
typedef __attribute__((ext_vector_type(8))) u16 u16x8;
typedef __attribute__((ext_vector_type(4))) u16 u16x4;
typedef __attribute__((ext_vector_type(4))) float f32x4;

#define DEV static __device__ __forceinline__

DEV u16 f2bf(float f) {
  unsigned u = __builtin_bit_cast(unsigned, f);
  u += 0x7FFFu + ((u >> 16) & 1u);
  return (u16)(u >> 16);
}

DEV f32x4 mfma16(bf16x8 a, bf16x8 b, f32x4 c) {
  return __builtin_amdgcn_mfma_f32_16x16x32_bf16(a, b, c, 0, 0, 0);
}

DEV void gload_lds16(const u16* g, u16* lds) {
  __builtin_amdgcn_global_load_lds(
      (const __attribute__((address_space(1))) void*)g,
      (__attribute__((address_space(3))) void*)lds, 16, 0, 0);
}

// ---- fp32 -> bf16 bulk convert (n % 4 == 0)
__global__ __launch_bounds__(256) void cvt_f2bf(const float* __restrict__ s,
                                                u16* __restrict__ d, int n) {
  int i = (blockIdx.x * 256 + threadIdx.x) * 4;
  if (i >= n) return;
  float4 v = *(const float4*)(s + i);
  u16x4 o = {f2bf(v.x), f2bf(v.y), f2bf(v.z), f2bf(v.w)};
  *(u16x4*)(d + i) = o;
}

// ---- wo_w (nrow_real x ncol) fp32 -> bf16, padded to nrow_pad rows (zeros)
__global__ __launch_bounds__(256) void cvt_pad(const float* __restrict__ s,
                                               u16* __restrict__ d,
                                               int nrow_real, int nrow_pad, int ncol) {
  int i = (blockIdx.x * 256 + threadIdx.x) * 4;
  if (i >= nrow_pad * ncol) return;
  int row = i / ncol;
  u16x4 o;
  if (row < nrow_real) {
    float4 v = *(const float4*)(s + i);
    o = (u16x4){f2bf(v.x), f2bf(v.y), f2bf(v.z), f2bf(v.w)};
  } else {
    o = (u16x4){0, 0, 0, 0};
  }
  *(u16x4*)(d + i) = o;
}

// ---- C[M][Nreal] = A[M][K] * B[N][K]^T + bias.  A,B bf16 (K-major), C fp32.
// M%128==0, N%128==0 (B padded), K%64==0. 128x128 tile, BK=64, 4 waves.
__global__ __launch_bounds__(256) void gemm_bt(const u16* __restrict__ A,
                                               const u16* __restrict__ B,
                                               const float* __restrict__ bias,
                                               float* __restrict__ C,
                                               int M, int N, int K, int Nreal, int ldc) {
  __shared__ u16 smA[128 * 64];
  __shared__ u16 smB[128 * 64];
  int nbn = N >> 7;
  int bm = blockIdx.x / nbn, bn = blockIdx.x % nbn;
  int t = threadIdx.x, lane = t & 63, wv = t >> 6;
  int wr = wv >> 1, wc = wv & 1;
  int l15 = lane & 15, hi = lane >> 4;
  f32x4 acc[4][4] = {};
  const u16* Ab = A + (size_t)(bm * 128 + (t >> 3)) * K + (t & 7) * 8;
  const u16* Bb = B + (size_t)(bn * 128 + (t >> 3)) * K + (t & 7) * 8;
  for (int k0 = 0; k0 < K; k0 += 64) {
#pragma unroll
    for (int i = 0; i < 4; i++) {
      gload_lds16(Ab + k0 + (size_t)i * 32 * K, smA + i * 2048 + t * 8);
      gload_lds16(Bb + k0 + (size_t)i * 32 * K, smB + i * 2048 + t * 8);
    }
    __syncthreads();
#pragma unroll
    for (int kk = 0; kk < 2; kk++) {
      bf16x8 af[4], bfr[4];
#pragma unroll
      for (int m = 0; m < 4; m++)
        af[m] = *(const bf16x8*)(smA + (wr * 64 + m * 16 + l15) * 64 + kk * 32 + hi * 8);
#pragma unroll
      for (int n = 0; n < 4; n++)
        bfr[n] = *(const bf16x8*)(smB + (wc * 64 + n * 16 + l15) * 64 + kk * 32 + hi * 8);
#pragma unroll
      for (int m = 0; m < 4; m++)
#pragma unroll
        for (int n = 0; n < 4; n++)
          acc[m][n] = mfma16(af[m], bfr[n], acc[m][n]);
    }
    __syncthreads();
  }
  int r0 = bm * 128 + wr * 64 + hi * 4;
  int c0 = bn * 128 + wc * 64 + l15;
#pragma unroll
  for (int n = 0; n < 4; n++) {
    int col = c0 + n * 16;
    if (col >= Nreal) continue;
    float bv = bias[col];
#pragma unroll
    for (int m = 0; m < 4; m++) {
#pragma unroll
      for (int r = 0; r < 4; r++) {
        C[(size_t)(r0 + m * 16 + r) * ldc + col] = acc[m][n][r] + bv;
      }
    }
  }
}

// ---- src [S][H*64] fp32 -> dst [H][S][64] bf16 with RoPE (rotate-half), scaled
__global__ __launch_bounds__(256) void rope_tr(const float* __restrict__ src,
                                               const float* __restrict__ rope,
                                               u16* __restrict__ dst,
                                               int S, int H, float scale) {
  int i = blockIdx.x * 256 + threadIdx.x;
  if (i >= S * H * 64) return;
  int d = i & 63;
  int s = (i >> 6) % S;
  int h = i / (S * 64);
  int ld = H * 64;
  float q = src[(size_t)s * ld + h * 64 + d];
  float qp = src[(size_t)s * ld + h * 64 + ((d + 32) & 63)];
  float c = rope[s * 128 + d];
  float sn = rope[s * 128 + 64 + d];
  float r = (d < 32) ? (q * c - qp * sn) : (q * c + qp * sn);
  dst[i] = f2bf(r * scale);
}

// ---- src [S][H*64] fp32 -> dst [H][S][64] bf16 (V transpose)
__global__ __launch_bounds__(256) void cast_tr(const float* __restrict__ src,
                                               u16* __restrict__ dst, int S, int H) {
  int i = blockIdx.x * 256 + threadIdx.x;
  if (i >= S * H * 64) return;
  int d = i & 63;
  int s = (i >> 6) % S;
  int h = i / (S * 64);
  dst[i] = f2bf(src[(size_t)s * (H * 64) + h * 64 + d]);
}

// ---- flash attention fwd: block = (64 q-rows, 1 head), 4 waves x 16 rows.
// Q pre-scaled by 1/8. KV tiles of 32. Online softmax; LSE for sink rescale.
// Out: [S][H*64] bf16.
__global__ __launch_bounds__(256) void attn_fwd(const u16* __restrict__ Q,
                                                const u16* __restrict__ K,
                                                const u16* __restrict__ V,
                                                const float* __restrict__ sinks,
                                                u16* __restrict__ Out,
                                                int S, int H, int Hkv) {
  __shared__ u16 ldsK[32 * 64];
  __shared__ u16 ldsVT[64 * 32];
  __shared__ u16 ldsP[4 * 16 * 32];
  int qb = blockIdx.x, h = blockIdx.y;
  int hkv = h / (H / Hkv);
  int t = threadIdx.x, lane = t & 63, wv = t >> 6;
  int l15 = lane & 15, hi = lane >> 4;
  int q0 = qb * 64 + wv * 16;
  const u16* Qh = Q + ((size_t)h * S + q0) * 64;
  const u16* Kh = K + (size_t)hkv * S * 64;
  const u16* Vh = V + (size_t)hkv * S * 64;
  bf16x8 qf0 = *(const bf16x8*)(Qh + l15 * 64 + hi * 8);
  bf16x8 qf1 = *(const bf16x8*)(Qh + l15 * 64 + 32 + hi * 8);
  float m[4], l[4];
  f32x4 ao[4] = {};
#pragma unroll
  for (int r = 0; r < 4; r++) { m[r] = -1e30f; l[r] = 0.f; }
  int kbmax = (qb * 64 + 63) >> 5;
  int krow = t >> 3, kcol = (t & 7) * 8;
  for (int kb = 0; kb <= kbmax; kb++) {
    __syncthreads();
    {
      int k0 = kb * 32;
      *(u16x8*)(ldsK + krow * 64 + kcol) =
          *(const u16x8*)(Kh + (size_t)(k0 + krow) * 64 + kcol);
      u16x8 vvv = *(const u16x8*)(Vh + (size_t)(k0 + krow) * 64 + kcol);
#pragma unroll
      for (int j = 0; j < 8; j++) ldsVT[(kcol + j) * 32 + krow] = vvv[j];
    }
    __syncthreads();
    // QK^T: S-tile 16(q) x 32(k), rows in (hi*4+reg), cols in l15 (+16)
    f32x4 s0 = {}, s1 = {};
    {
      bf16x8 b00 = *(const bf16x8*)(ldsK + l15 * 64 + hi * 8);
      bf16x8 b10 = *(const bf16x8*)(ldsK + (l15 + 16) * 64 + hi * 8);
      s0 = mfma16(qf0, b00, s0);
      s1 = mfma16(qf0, b10, s1);
      bf16x8 b01 = *(const bf16x8*)(ldsK + l15 * 64 + 32 + hi * 8);
      bf16x8 b11 = *(const bf16x8*)(ldsK + (l15 + 16) * 64 + 32 + hi * 8);
      s0 = mfma16(qf1, b01, s0);
      s1 = mfma16(qf1, b11, s1);
    }
    int col0 = kb * 32 + l15, col1 = col0 + 16;
    float al[4];
#pragma unroll
    for (int r = 0; r < 4; r++) {
      int rowq = q0 + hi * 4 + r;
      float a = (col0 <= rowq) ? s0[r] : -1e30f;
      float b = (col1 <= rowq) ? s1[r] : -1e30f;
      float tmx = fmaxf(a, b);
#pragma unroll
      for (int off = 1; off < 16; off <<= 1) tmx = fmaxf(tmx, __shfl_xor(tmx, off));
      float mn = fmaxf(m[r], tmx);
      float p0 = __expf(a - mn), p1 = __expf(b - mn);
      al[r] = __expf(m[r] - mn);
      float rs = p0 + p1;
#pragma unroll
      for (int off = 1; off < 16; off <<= 1) rs += __shfl_xor(rs, off);
      l[r] = l[r] * al[r] + rs;
      m[r] = mn;
      ldsP[wv * 512 + (hi * 4 + r) * 32 + l15] = f2bf(p0);
      ldsP[wv * 512 + (hi * 4 + r) * 32 + l15 + 16] = f2bf(p1);
    }
#pragma unroll
    for (int nt = 0; nt < 4; nt++)
#pragma unroll
      for (int r = 0; r < 4; r++) ao[nt][r] *= al[r];
    __syncthreads();
    // PV: A = P[16q][32k] from ldsP, B = V[32k][64d] via ldsVT
    bf16x8 pa = *(const bf16x8*)(ldsP + wv * 512 + l15 * 32 + hi * 8);
#pragma unroll
    for (int nt = 0; nt < 4; nt++) {
      bf16x8 bv = *(const bf16x8*)(ldsVT + (nt * 16 + l15) * 32 + hi * 8);
      ao[nt] = mfma16(pa, bv, ao[nt]);
    }
  }
  float snk = sinks[h];
#pragma unroll
  for (int r = 0; r < 4; r++) {
    float lse = m[r] + __logf(l[r]);
    float ss = 1.f / (1.f + __expf(snk - lse));
    float f = ss / l[r];
    int row = q0 + hi * 4 + r;
#pragma unroll
    for (int nt = 0; nt < 4; nt++)
      Out[(size_t)row * (H * 64) + h * 64 + nt * 16 + l15] = f2bf(ao[nt][r] * f);
  }
}

extern "C" void kernel_launch(void* const* d_in, const int* in_sizes, int n_in,
                              void* d_out, int out_size, void* d_ws, size_t ws_size,
                              hipStream_t stream) {
  const int S = 1536, HID = 2880, H = 64, HKV = 8;
  const int NQ = 4096, NKV = 512, NPAD = 2944;

  const float* x     = (const float*)d_in[0];
  const float* rope  = (const float*)d_in[1];
  const float* wq_w  = (const float*)d_in[2];
  const float* wq_b  = (const float*)d_in[3];
  const float* wk_w  = (const float*)d_in[4];
  const float* wk_b  = (const float*)d_in[5];
  const float* wv_w  = (const float*)d_in[6];
  const float* wv_b  = (const float*)d_in[7];
  const float* wo_w  = (const float*)d_in[8];
  const float* wo_b  = (const float*)d_in[9];
  const float* sinks = (const float*)d_in[10];
  float* out = (float*)d_out;

  char* ws = (char*)d_ws;
  size_t off = 0;
  auto alloc = [&](size_t bytes) {
    char* p = ws + off;
    off = (off + bytes + 255) & ~(size_t)255;
    return p;
  };
  u16*   x_bf  = (u16*)  alloc((size_t)S * HID * 2);
  u16*   wq_bf = (u16*)  alloc((size_t)NQ * HID * 2);
  u16*   wk_bf = (u16*)  alloc((size_t)NKV * HID * 2);
  u16*   wv_bf = (u16*)  alloc((size_t)NKV * HID * 2);
  u16*   wo_bf = (u16*)  alloc((size_t)NPAD * NQ * 2);
  float* q_raw = (float*)alloc((size_t)S * NQ * 4);
  float* k_raw = (float*)alloc((size_t)S * NKV * 4);
  float* v_raw = (float*)alloc((size_t)S * NKV * 4);
  u16*   Qb    = (u16*)  alloc((size_t)H * S * 64 * 2);
  u16*   Kb    = (u16*)  alloc((size_t)HKV * S * 64 * 2);
  u16*   Vb    = (u16*)  alloc((size_t)HKV * S * 64 * 2);
  u16*   att   = (u16*)  alloc((size_t)S * NQ * 2);
  (void)ws_size; (void)n_in; (void)in_sizes; (void)out_size;

  auto cdiv = [](int a, int b) { return (a + b - 1) / b; };

  cvt_f2bf<<<cdiv(S * HID / 4, 256), 256, 0, stream>>>(x, x_bf, S * HID);
  cvt_f2bf<<<cdiv(NQ * HID / 4, 256), 256, 0, stream>>>(wq_w, wq_bf, NQ * HID);
  cvt_f2bf<<<cdiv(NKV * HID / 4, 256), 256, 0, stream>>>(wk_w, wk_bf, NKV * HID);
  cvt_f2bf<<<cdiv(NKV * HID / 4, 256), 256, 0, stream>>>(wv_w, wv_bf, NKV * HID);
  cvt_pad<<<cdiv(NPAD * NQ / 4, 256), 256, 0, stream>>>(wo_w, wo_bf, HID, NPAD, NQ);

  gemm_bt<<<(S / 128) * (NQ / 128), 256, 0, stream>>>(x_bf, wq_bf, wq_b, q_raw,
                                                      S, NQ, HID, NQ, NQ);
  gemm_bt<<<(S / 128) * (NKV / 128), 256, 0, stream>>>(x_bf, wk_bf, wk_b, k_raw,
                                                       S, NKV, HID, NKV, NKV);
  gemm_bt<<<(S / 128) * (NKV / 128), 256, 0, stream>>>(x_bf, wv_bf, wv_b, v_raw,
                                                       S, NKV, HID, NKV, NKV);

  rope_tr<<<cdiv(S * NQ, 256), 256, 0, stream>>>(q_raw, rope, Qb, S, H, 0.125f);
  rope_tr<<<cdiv(S * NKV, 256), 256, 0, stream>>>(k_raw, rope, Kb, S, HKV, 1.0f);
  cast_tr<<<cdiv(S * NKV, 256), 256, 0, stream>>>(v_raw, Vb, S, HKV);

  attn_fwd<<<dim3(S / 64, H), 256, 0, stream>>>(Qb, Kb, Vb, sinks, att, S, H, HKV);

  gemm_bt<<<(S / 128) * (NPAD / 128), 256, 0, stream>>>(att, wo_bf, wo_b, out,
                                                        S, NPAD, NQ, HID, HID);
}

// Round 2
// 448.966 us; speedup vs baseline: 1.2150x; 1.2150x over previous
//
#include <hip/hip_runtime.h>

typedef unsigned short u16;
typedef __attribute__((ext_vector_type(8))) __bf16 bf16x8;
typedef __attribute__((ext_vector_type(8))) u16 u16x8;
typedef __attribute__((ext_vector_type(4))) u16 u16x4;
typedef __attribute__((ext_vector_type(4))) float f32x4;

#define DEV static __device__ __forceinline__

DEV u16 f2bf(float f) {
  unsigned u = __builtin_bit_cast(unsigned, f);
  u += 0x7FFFu + ((u >> 16) & 1u);
  return (u16)(u >> 16);
}

DEV f32x4 mfma16(bf16x8 a, bf16x8 b, f32x4 c) {
  return __builtin_amdgcn_mfma_f32_16x16x32_bf16(a, b, c, 0, 0, 0);
}

DEV void gload_lds16(const u16* g, u16* lds) {
  __builtin_amdgcn_global_load_lds(
      (const __attribute__((address_space(1))) void*)g,
      (__attribute__((address_space(3))) void*)lds, 16, 0, 0);
}

// ---- fp32 -> bf16 bulk convert (n % 4 == 0)
__global__ __launch_bounds__(256) void cvt_f2bf(const float* __restrict__ s,
                                                u16* __restrict__ d, int n) {
  int i = (blockIdx.x * 256 + threadIdx.x) * 4;
  if (i >= n) return;
  float4 v = *(const float4*)(s + i);
  u16x4 o = {f2bf(v.x), f2bf(v.y), f2bf(v.z), f2bf(v.w)};
  *(u16x4*)(d + i) = o;
}

// ---- wo_w (nrow_real x ncol) fp32 -> bf16, padded to nrow_pad rows (zeros)
__global__ __launch_bounds__(256) void cvt_pad(const float* __restrict__ s,
                                               u16* __restrict__ d,
                                               int nrow_real, int nrow_pad, int ncol) {
  int i = (blockIdx.x * 256 + threadIdx.x) * 4;
  if (i >= nrow_pad * ncol) return;
  int row = i / ncol;
  u16x4 o;
  if (row < nrow_real) {
    float4 v = *(const float4*)(s + i);
    o = (u16x4){f2bf(v.x), f2bf(v.y), f2bf(v.z), f2bf(v.w)};
  } else {
    o = (u16x4){0, 0, 0, 0};
  }
  *(u16x4*)(d + i) = o;
}

// ---- C[M][Nreal] = A[M][K] * B[N][K]^T + bias.  A,B bf16 (K-major), C fp32.
__global__ __launch_bounds__(256) void gemm_bt(const u16* __restrict__ A,
                                               const u16* __restrict__ B,
                                               const float* __restrict__ bias,
                                               float* __restrict__ C,
                                               int M, int N, int K, int Nreal, int ldc) {
  __shared__ u16 smA[128 * 64];
  __shared__ u16 smB[128 * 64];
  int nbn = N >> 7;
  int bm = blockIdx.x / nbn, bn = blockIdx.x % nbn;
  int t = threadIdx.x, lane = t & 63, wv = t >> 6;
  int wr = wv >> 1, wc = wv & 1;
  int l15 = lane & 15, hi = lane >> 4;
  f32x4 acc[4][4] = {};
  const u16* Ab = A + (size_t)(bm * 128 + (t >> 3)) * K + (t & 7) * 8;
  const u16* Bb = B + (size_t)(bn * 128 + (t >> 3)) * K + (t & 7) * 8;
  for (int k0 = 0; k0 < K; k0 += 64) {
#pragma unroll
    for (int i = 0; i < 4; i++) {
      gload_lds16(Ab + k0 + (size_t)i * 32 * K, smA + i * 2048 + t * 8);
      gload_lds16(Bb + k0 + (size_t)i * 32 * K, smB + i * 2048 + t * 8);
    }
    __syncthreads();
#pragma unroll
    for (int kk = 0; kk < 2; kk++) {
      bf16x8 af[4], bfr[4];
#pragma unroll
      for (int m = 0; m < 4; m++)
        af[m] = *(const bf16x8*)(smA + (wr * 64 + m * 16 + l15) * 64 + kk * 32 + hi * 8);
#pragma unroll
      for (int n = 0; n < 4; n++)
        bfr[n] = *(const bf16x8*)(smB + (wc * 64 + n * 16 + l15) * 64 + kk * 32 + hi * 8);
#pragma unroll
      for (int m = 0; m < 4; m++)
#pragma unroll
        for (int n = 0; n < 4; n++)
          acc[m][n] = mfma16(af[m], bfr[n], acc[m][n]);
    }
    __syncthreads();
  }
  int r0 = bm * 128 + wr * 64 + hi * 4;
  int c0 = bn * 128 + wc * 64 + l15;
#pragma unroll
  for (int n = 0; n < 4; n++) {
    int col = c0 + n * 16;
    if (col >= Nreal) continue;
    float bv = bias[col];
#pragma unroll
    for (int m = 0; m < 4; m++) {
#pragma unroll
      for (int r = 0; r < 4; r++) {
        C[(size_t)(r0 + m * 16 + r) * ldc + col] = acc[m][n][r] + bv;
      }
    }
  }
}

// ---- src [S][H*64] fp32 -> dst [H][S][64] bf16 with RoPE (rotate-half), scaled
__global__ __launch_bounds__(256) void rope_tr(const float* __restrict__ src,
                                               const float* __restrict__ rope,
                                               u16* __restrict__ dst,
                                               int S, int H, float scale) {
  int i = blockIdx.x * 256 + threadIdx.x;
  if (i >= S * H * 64) return;
  int d = i & 63;
  int s = (i >> 6) % S;
  int h = i / (S * 64);
  int ld = H * 64;
  float q = src[(size_t)s * ld + h * 64 + d];
  float qp = src[(size_t)s * ld + h * 64 + ((d + 32) & 63)];
  float c = rope[s * 128 + d];
  float sn = rope[s * 128 + 64 + d];
  float r = (d < 32) ? (q * c - qp * sn) : (q * c + qp * sn);
  dst[i] = f2bf(r * scale);
}

// ---- V transpose: src [S][Hkv*64] fp32 -> dst [Hkv][64][S] bf16 (LDS-tiled)
__global__ __launch_bounds__(256) void cast_trT(const float* __restrict__ src,
                                                u16* __restrict__ dst, int S, int Hkv) {
  __shared__ u16 tile[64][65];
  int s0 = blockIdx.x * 64;
  int hkv = blockIdx.y;
  int t = threadIdx.x;
  int ld = Hkv * 64;
  int dl = (t & 15) * 4;
  int sl = t >> 4;
#pragma unroll
  for (int j = 0; j < 4; j++) {
    int s = sl + j * 16;
    float4 v = *(const float4*)(src + (size_t)(s0 + s) * ld + hkv * 64 + dl);
    tile[dl + 0][s] = f2bf(v.x);
    tile[dl + 1][s] = f2bf(v.y);
    tile[dl + 2][s] = f2bf(v.z);
    tile[dl + 3][s] = f2bf(v.w);
  }
  __syncthreads();
  int sl2 = (t & 7) * 8;
  int dl2 = t >> 3;
#pragma unroll
  for (int j = 0; j < 2; j++) {
    int d = dl2 + j * 32;
    u16x8 o;
#pragma unroll
    for (int c = 0; c < 8; c++) o[c] = tile[d][sl2 + c];
    *(u16x8*)(dst + ((size_t)hkv * 64 + d) * S + s0 + sl2) = o;
  }
}

// ---- flash attention fwd: block = (64 q-rows, 1 head), 4 waves x 16 rows.
// Q pre-scaled by 1/8. KV tiles of 64, double-buffered, XOR-swizzled LDS.
// K: [Hkv][S][64], VT: [Hkv][64][S]. Out: [S][H*64] bf16.
__global__ __launch_bounds__(256) void attn_fwd(const u16* __restrict__ Q,
                                                const u16* __restrict__ K,
                                                const u16* __restrict__ VT,
                                                const float* __restrict__ sinks,
                                                u16* __restrict__ Out,
                                                int S, int H, int Hkv) {
  __shared__ u16 ldsK[2][64 * 64];
  __shared__ u16 ldsV[2][64 * 64];  // V^T tile: [d][k]
  __shared__ u16 ldsP[4][16 * 64];
  int qb = gridDim.x - 1 - blockIdx.x;  // long blocks first
  int h = blockIdx.y;
  int hkv = h / (H / Hkv);
  int t = threadIdx.x, lane = t & 63, wv = t >> 6;
  int l15 = lane & 15, hi = lane >> 4;
  int q0 = qb * 64 + wv * 16;
  const u16* Qh = Q + ((size_t)h * S + q0) * 64;
  const u16* Kh = K + (size_t)hkv * S * 64;
  const u16* VTh = VT + (size_t)hkv * 64 * S;
  u16* ldsPw = &ldsP[wv][0];

  bf16x8 qf[2];
  qf[0] = *(const bf16x8*)(Qh + l15 * 64 + hi * 8);
  qf[1] = *(const bf16x8*)(Qh + l15 * 64 + 32 + hi * 8);

  float m[4], l[4];
  f32x4 ao[4] = {};
#pragma unroll
  for (int r = 0; r < 4; r++) { m[r] = -1e30f; l[r] = 0.f; }

  // stage tile kb into buffer b: LDS linear, global source pre-swizzled
  auto stage = [&](int b, int kb) {
    int k0 = kb * 64;
#pragma unroll
    for (int i = 0; i < 2; i++) {
      int c = i * 256 + t;
      int row = c >> 3, c16 = c & 7;
      int sc = (c16 ^ (row & 7)) * 8;
      gload_lds16(Kh + (size_t)(k0 + row) * 64 + sc, &ldsK[b][c * 8]);
      gload_lds16(VTh + (size_t)row * S + k0 + sc, &ldsV[b][c * 8]);
    }
  };

  stage(0, 0);
  for (int kb = 0; kb <= qb; kb++) {
    int cur = kb & 1;
    __syncthreads();  // drains vmcnt: tile kb staged; prev readers of buf cur^1 done
    if (kb < qb) stage(cur ^ 1, kb + 1);  // async prefetch, hides under compute

    // QK^T: s[ct] covers k-cols [kb*64 + ct*16 .. +16)
    f32x4 s[4] = {};
#pragma unroll
    for (int kk = 0; kk < 2; kk++) {
#pragma unroll
      for (int ct = 0; ct < 4; ct++) {
        int row = ct * 16 + l15;
        int c16 = (kk * 4 + hi) ^ (row & 7);
        bf16x8 kf = *(const bf16x8*)(&ldsK[cur][row * 64 + c16 * 8]);
        s[ct] = mfma16(qf[kk], kf, s[ct]);
      }
    }

    bool full = (kb * 64 + 63) < q0;  // wave-uniform: whole tile unmasked
    float al[4];
#pragma unroll
    for (int r = 0; r < 4; r++) {
      int rowq = q0 + hi * 4 + r;
      float v0 = s[0][r], v1 = s[1][r], v2 = s[2][r], v3 = s[3][r];
      if (!full) {
        int col = kb * 64 + l15;
        v0 = (col <= rowq) ? v0 : -1e30f;
        v1 = (col + 16 <= rowq) ? v1 : -1e30f;
        v2 = (col + 32 <= rowq) ? v2 : -1e30f;
        v3 = (col + 48 <= rowq) ? v3 : -1e30f;
      }
      float tmx = fmaxf(fmaxf(v0, v1), fmaxf(v2, v3));
#pragma unroll
      for (int off = 1; off < 16; off <<= 1) tmx = fmaxf(tmx, __shfl_xor(tmx, off));
      float mn = fmaxf(m[r], tmx);
      float p0 = __expf(v0 - mn), p1 = __expf(v1 - mn);
      float p2 = __expf(v2 - mn), p3 = __expf(v3 - mn);
      al[r] = __expf(m[r] - mn);
      float rs = p0 + p1 + p2 + p3;
#pragma unroll
      for (int off = 1; off < 16; off <<= 1) rs += __shfl_xor(rs, off);
      l[r] = l[r] * al[r] + rs;
      m[r] = mn;
      int prow = hi * 4 + r;
      int sw = (prow & 7) << 4;
      ldsPw[(prow * 128 + ((0 * 32 + l15 * 2) ^ sw)) >> 1] = f2bf(p0);
      ldsPw[(prow * 128 + ((1 * 32 + l15 * 2) ^ sw)) >> 1] = f2bf(p1);
      ldsPw[(prow * 128 + ((2 * 32 + l15 * 2) ^ sw)) >> 1] = f2bf(p2);
      ldsPw[(prow * 128 + ((3 * 32 + l15 * 2) ^ sw)) >> 1] = f2bf(p3);
    }
#pragma unroll
    for (int nt = 0; nt < 4; nt++)
#pragma unroll
      for (int r = 0; r < 4; r++) ao[nt][r] *= al[r];

    // PV (ldsP is per-wave: no barrier; same-wave DS ordering + lgkmcnt)
#pragma unroll
    for (int kk = 0; kk < 2; kk++) {
      int c16p = (kk * 4 + hi) ^ (l15 & 7);
      bf16x8 pa = *(const bf16x8*)(&ldsPw[l15 * 64 + c16p * 8]);
#pragma unroll
      for (int nt = 0; nt < 4; nt++) {
        int vrow = nt * 16 + l15;
        int c16 = (kk * 4 + hi) ^ (vrow & 7);
        bf16x8 vf = *(const bf16x8*)(&ldsV[cur][vrow * 64 + c16 * 8]);
        ao[nt] = mfma16(pa, vf, ao[nt]);
      }
    }
  }

  float snk = sinks[h];
#pragma unroll
  for (int r = 0; r < 4; r++) {
    float lse = m[r] + __logf(l[r]);
    float ss = 1.f / (1.f + __expf(snk - lse));
    float f = ss / l[r];
    int row = q0 + hi * 4 + r;
#pragma unroll
    for (int nt = 0; nt < 4; nt++)
      Out[(size_t)row * (H * 64) + h * 64 + nt * 16 + l15] = f2bf(ao[nt][r] * f);
  }
}

extern "C" void kernel_launch(void* const* d_in, const int* in_sizes, int n_in,
                              void* d_out, int out_size, void* d_ws, size_t ws_size,
                              hipStream_t stream) {
  const int S = 1536, HID = 2880, H = 64, HKV = 8;
  const int NQ = 4096, NKV = 512, NPAD = 2944;

  const float* x     = (const float*)d_in[0];
  const float* rope  = (const float*)d_in[1];
  const float* wq_w  = (const float*)d_in[2];
  const float* wq_b  = (const float*)d_in[3];
  const float* wk_w  = (const float*)d_in[4];
  const float* wk_b  = (const float*)d_in[5];
  const float* wv_w  = (const float*)d_in[6];
  const float* wv_b  = (const float*)d_in[7];
  const float* wo_w  = (const float*)d_in[8];
  const float* wo_b  = (const float*)d_in[9];
  const float* sinks = (const float*)d_in[10];
  float* out = (float*)d_out;

  char* ws = (char*)d_ws;
  size_t off = 0;
  auto alloc = [&](size_t bytes) {
    char* p = ws + off;
    off = (off + bytes + 255) & ~(size_t)255;
    return p;
  };
  u16*   x_bf  = (u16*)  alloc((size_t)S * HID * 2);
  u16*   wq_bf = (u16*)  alloc((size_t)NQ * HID * 2);
  u16*   wk_bf = (u16*)  alloc((size_t)NKV * HID * 2);
  u16*   wv_bf = (u16*)  alloc((size_t)NKV * HID * 2);
  u16*   wo_bf = (u16*)  alloc((size_t)NPAD * NQ * 2);
  float* q_raw = (float*)alloc((size_t)S * NQ * 4);
  float* k_raw = (float*)alloc((size_t)S * NKV * 4);
  float* v_raw = (float*)alloc((size_t)S * NKV * 4);
  u16*   Qb    = (u16*)  alloc((size_t)H * S * 64 * 2);
  u16*   Kb    = (u16*)  alloc((size_t)HKV * S * 64 * 2);
  u16*   VTb   = (u16*)  alloc((size_t)HKV * 64 * S * 2);
  u16*   att   = (u16*)  alloc((size_t)S * NQ * 2);
  (void)ws_size; (void)n_in; (void)in_sizes; (void)out_size;

  auto cdiv = [](int a, int b) { return (a + b - 1) / b; };

  cvt_f2bf<<<cdiv(S * HID / 4, 256), 256, 0, stream>>>(x, x_bf, S * HID);
  cvt_f2bf<<<cdiv(NQ * HID / 4, 256), 256, 0, stream>>>(wq_w, wq_bf, NQ * HID);
  cvt_f2bf<<<cdiv(NKV * HID / 4, 256), 256, 0, stream>>>(wk_w, wk_bf, NKV * HID);
  cvt_f2bf<<<cdiv(NKV * HID / 4, 256), 256, 0, stream>>>(wv_w, wv_bf, NKV * HID);
  cvt_pad<<<cdiv(NPAD * NQ / 4, 256), 256, 0, stream>>>(wo_w, wo_bf, HID, NPAD, NQ);

  gemm_bt<<<(S / 128) * (NQ / 128), 256, 0, stream>>>(x_bf, wq_bf, wq_b, q_raw,
                                                      S, NQ, HID, NQ, NQ);
  gemm_bt<<<(S / 128) * (NKV / 128), 256, 0, stream>>>(x_bf, wk_bf, wk_b, k_raw,
                                                       S, NKV, HID, NKV, NKV);
  gemm_bt<<<(S / 128) * (NKV / 128), 256, 0, stream>>>(x_bf, wv_bf, wv_b, v_raw,
                                                       S, NKV, HID, NKV, NKV);

  rope_tr<<<cdiv(S * NQ, 256), 256, 0, stream>>>(q_raw, rope, Qb, S, H, 0.125f);
  rope_tr<<<cdiv(S * NKV, 256), 256, 0, stream>>>(k_raw, rope, Kb, S, HKV, 1.0f);
  cast_trT<<<dim3(S / 64, HKV), 256, 0, stream>>>(v_raw, VTb, S, HKV);

  attn_fwd<<<dim3(S / 64, H), 256, 0, stream>>>(Qb, Kb, VTb, sinks, att, S, H, HKV);

  gemm_bt<<<(S / 128) * (NPAD / 128), 256, 0, stream>>>(att, wo_bf, wo_b, out,
                                                        S, NPAD, NQ, HID, HID);
}

// Round 3
// 299.702 us; speedup vs baseline: 1.8202x; 1.4980x over previous
//
#include <hip/hip_runtime.h>

typedef unsigned short u16;
typedef __attribute__((ext_vector_type(8))) __bf16 bf16x8;
typedef __attribute__((ext_vector_type(8))) u16 u16x8;
typedef __attribute__((ext_vector_type(4))) u16 u16x4;
typedef __attribute__((ext_vector_type(4))) float f32x4;

#define DEV static __device__ __forceinline__

DEV u16 f2bf(float f) {
  unsigned u = __builtin_bit_cast(unsigned, f);
  u += 0x7FFFu + ((u >> 16) & 1u);
  return (u16)(u >> 16);
}

DEV f32x4 mfma16(bf16x8 a, bf16x8 b, f32x4 c) {
  return __builtin_amdgcn_mfma_f32_16x16x32_bf16(a, b, c, 0, 0, 0);
}

DEV f32x4 fmax4(f32x4 a, f32x4 b) {
  f32x4 r;
  r[0] = fmaxf(a[0], b[0]); r[1] = fmaxf(a[1], b[1]);
  r[2] = fmaxf(a[2], b[2]); r[3] = fmaxf(a[3], b[3]);
  return r;
}

DEV void gload_lds16(const u16* g, u16* lds) {
  __builtin_amdgcn_global_load_lds(
      (const __attribute__((address_space(1))) void*)g,
      (__attribute__((address_space(3))) void*)lds, 16, 0, 0);
}

// ---- fp32 -> bf16 bulk convert (n % 4 == 0)
__global__ __launch_bounds__(256) void cvt_f2bf(const float* __restrict__ s,
                                                u16* __restrict__ d, int n) {
  int i = (blockIdx.x * 256 + threadIdx.x) * 4;
  if (i >= n) return;
  float4 v = *(const float4*)(s + i);
  u16x4 o = {f2bf(v.x), f2bf(v.y), f2bf(v.z), f2bf(v.w)};
  *(u16x4*)(d + i) = o;
}

// ---- wo_w (nrow_real x ncol) fp32 -> bf16, padded to nrow_pad rows (zeros)
__global__ __launch_bounds__(256) void cvt_pad(const float* __restrict__ s,
                                               u16* __restrict__ d,
                                               int nrow_real, int nrow_pad, int ncol) {
  int i = (blockIdx.x * 256 + threadIdx.x) * 4;
  if (i >= nrow_pad * ncol) return;
  int row = i / ncol;
  u16x4 o;
  if (row < nrow_real) {
    float4 v = *(const float4*)(s + i);
    o = (u16x4){f2bf(v.x), f2bf(v.y), f2bf(v.z), f2bf(v.w)};
  } else {
    o = (u16x4){0, 0, 0, 0};
  }
  *(u16x4*)(d + i) = o;
}

// ---- pack q/k/v biases into one [5120] vector
__global__ __launch_bounds__(256) void pack_bias(const float* __restrict__ q,
                                                 const float* __restrict__ k,
                                                 const float* __restrict__ v,
                                                 float* __restrict__ o) {
  int i = blockIdx.x * 256 + threadIdx.x;
  if (i >= 5120) return;
  o[i] = (i < 4096) ? q[i] : (i < 4608 ? k[i - 4096] : v[i - 4608]);
}

// ---- C[M][Nreal] = A[M][K] * B[N][K]^T + bias.  A,B bf16 (K-major), C fp32.
__global__ __launch_bounds__(256) void gemm_bt(const u16* __restrict__ A,
                                               const u16* __restrict__ B,
                                               const float* __restrict__ bias,
                                               float* __restrict__ C,
                                               int M, int N, int K, int Nreal, int ldc) {
  __shared__ u16 smA[128 * 64];
  __shared__ u16 smB[128 * 64];
  int nbn = N >> 7;
  int bm = blockIdx.x / nbn, bn = blockIdx.x % nbn;
  int t = threadIdx.x, lane = t & 63, wv = t >> 6;
  int wr = wv >> 1, wc = wv & 1;
  int l15 = lane & 15, hi = lane >> 4;
  f32x4 acc[4][4] = {};
  const u16* Ab = A + (size_t)(bm * 128 + (t >> 3)) * K + (t & 7) * 8;
  const u16* Bb = B + (size_t)(bn * 128 + (t >> 3)) * K + (t & 7) * 8;
  for (int k0 = 0; k0 < K; k0 += 64) {
#pragma unroll
    for (int i = 0; i < 4; i++) {
      gload_lds16(Ab + k0 + (size_t)i * 32 * K, smA + i * 2048 + t * 8);
      gload_lds16(Bb + k0 + (size_t)i * 32 * K, smB + i * 2048 + t * 8);
    }
    __syncthreads();
#pragma unroll
    for (int kk = 0; kk < 2; kk++) {
      bf16x8 af[4], bfr[4];
#pragma unroll
      for (int m = 0; m < 4; m++)
        af[m] = *(const bf16x8*)(smA + (wr * 64 + m * 16 + l15) * 64 + kk * 32 + hi * 8);
#pragma unroll
      for (int n = 0; n < 4; n++)
        bfr[n] = *(const bf16x8*)(smB + (wc * 64 + n * 16 + l15) * 64 + kk * 32 + hi * 8);
#pragma unroll
      for (int m = 0; m < 4; m++)
#pragma unroll
        for (int n = 0; n < 4; n++)
          acc[m][n] = mfma16(af[m], bfr[n], acc[m][n]);
    }
    __syncthreads();
  }
  int r0 = bm * 128 + wr * 64 + hi * 4;
  int c0 = bn * 128 + wc * 64 + l15;
#pragma unroll
  for (int n = 0; n < 4; n++) {
    int col = c0 + n * 16;
    if (col >= Nreal) continue;
    float bv = bias[col];
#pragma unroll
    for (int m = 0; m < 4; m++) {
#pragma unroll
      for (int r = 0; r < 4; r++) {
        C[(size_t)(r0 + m * 16 + r) * ldc + col] = acc[m][n][r] + bv;
      }
    }
  }
}

// ---- src [S][ld] fp32 (cols col0..col0+H*64) -> dst [H][S][64] bf16, RoPE+scale
__global__ __launch_bounds__(256) void rope_tr(const float* __restrict__ src,
                                               const float* __restrict__ rope,
                                               u16* __restrict__ dst,
                                               int S, int H, int ld, int col0,
                                               float scale) {
  int i = blockIdx.x * 256 + threadIdx.x;
  if (i >= S * H * 64) return;
  int d = i & 63;
  int s = (i >> 6) % S;
  int h = i / (S * 64);
  const float* base = src + (size_t)s * ld + col0 + h * 64;
  float q = base[d];
  float qp = base[(d + 32) & 63];
  float c = rope[s * 128 + d];
  float sn = rope[s * 128 + 64 + d];
  float r = (d < 32) ? (q * c - qp * sn) : (q * c + qp * sn);
  dst[i] = f2bf(r * scale);
}

// ---- V transpose: src [S][ld] fp32 (cols col0+) -> dst [Hkv][64][S] bf16
__global__ __launch_bounds__(256) void cast_trT(const float* __restrict__ src,
                                                u16* __restrict__ dst, int S, int Hkv,
                                                int ld, int col0) {
  __shared__ u16 tile[64][65];
  int s0 = blockIdx.x * 64;
  int hkv = blockIdx.y;
  int t = threadIdx.x;
  int dl = (t & 15) * 4;
  int sl = t >> 4;
#pragma unroll
  for (int j = 0; j < 4; j++) {
    int s = sl + j * 16;
    float4 v = *(const float4*)(src + (size_t)(s0 + s) * ld + col0 + hkv * 64 + dl);
    tile[dl + 0][s] = f2bf(v.x);
    tile[dl + 1][s] = f2bf(v.y);
    tile[dl + 2][s] = f2bf(v.z);
    tile[dl + 3][s] = f2bf(v.w);
  }
  __syncthreads();
  int sl2 = (t & 7) * 8;
  int dl2 = t >> 3;
#pragma unroll
  for (int j = 0; j < 2; j++) {
    int d = dl2 + j * 32;
    u16x8 o;
#pragma unroll
    for (int c = 0; c < 8; c++) o[c] = tile[d][sl2 + c];
    *(u16x8*)(dst + ((size_t)hkv * 64 + d) * S + s0 + sl2) = o;
  }
}

// ---- flash attention fwd: block = (64 q-rows, 1 head), 4 waves x 16 rows.
// Swapped QK^T (mfma(K,Q)): each lane owns ONE q-row (l15) of scores ->
// in-register softmax reductions, only 2 shuffles per reduce.
// Q pre-scaled by 1/8. KV tiles of 64, double-buffered, XOR-swizzled LDS.
__global__ __launch_bounds__(256) void attn_fwd(const u16* __restrict__ Q,
                                                const u16* __restrict__ K,
                                                const u16* __restrict__ VT,
                                                const float* __restrict__ sinks,
                                                u16* __restrict__ Out,
                                                int S, int H, int Hkv) {
  __shared__ u16 ldsK[2][64 * 64];
  __shared__ u16 ldsV[2][64 * 64];  // V^T tile: [d][k]
  __shared__ u16 ldsP[4][16 * 64];
  int qb = gridDim.x - 1 - blockIdx.x;  // long blocks first
  int h = blockIdx.y;
  int hkv = h / (H / Hkv);
  int t = threadIdx.x, lane = t & 63, wv = t >> 6;
  int l15 = lane & 15, hi = lane >> 4;
  int q0 = qb * 64 + wv * 16;
  const u16* Qh = Q + ((size_t)h * S + q0) * 64;
  const u16* Kh = K + (size_t)hkv * S * 64;
  const u16* VTh = VT + (size_t)hkv * 64 * S;
  u16* ldsPw = &ldsP[wv][0];
  int psw = (l15 & 7) << 4;  // P swizzle for this lane's row

  bf16x8 qf[2];
  qf[0] = *(const bf16x8*)(Qh + l15 * 64 + hi * 8);
  qf[1] = *(const bf16x8*)(Qh + l15 * 64 + 32 + hi * 8);

  float mx = -1e30f, ls = 0.f;  // per-lane state for q-row (q0 + l15)
  f32x4 ao[4] = {};

  auto stage = [&](int b, int kb) {
    int k0 = kb * 64;
#pragma unroll
    for (int i = 0; i < 2; i++) {
      int c = i * 256 + t;
      int row = c >> 3, c16 = c & 7;
      int sc = (c16 ^ (row & 7)) * 8;
      gload_lds16(Kh + (size_t)(k0 + row) * 64 + sc, &ldsK[b][c * 8]);
      gload_lds16(VTh + (size_t)row * S + k0 + sc, &ldsV[b][c * 8]);
    }
  };

  int rowq = q0 + l15;
  stage(0, 0);
  for (int kb = 0; kb <= qb; kb++) {
    int cur = kb & 1;
    __syncthreads();  // tile kb staged; prev readers of buf cur^1 done
    if (kb < qb) stage(cur ^ 1, kb + 1);  // async prefetch under compute

    // QK^T swapped: s[ct][r] = score(q = q0+l15, k = kb*64 + ct*16 + hi*4 + r)
    f32x4 s[4] = {};
#pragma unroll
    for (int kk = 0; kk < 2; kk++) {
#pragma unroll
      for (int ct = 0; ct < 4; ct++) {
        int row = ct * 16 + l15;
        int c16 = (kk * 4 + hi) ^ (row & 7);
        bf16x8 kf = *(const bf16x8*)(&ldsK[cur][row * 64 + c16 * 8]);
        s[ct] = mfma16(kf, qf[kk], s[ct]);
      }
    }

    bool full = (kb * 64 + 63) < q0;  // wave-uniform: whole tile unmasked
    if (!full) {
      int kc = kb * 64 + hi * 4;
#pragma unroll
      for (int ct = 0; ct < 4; ct++)
#pragma unroll
        for (int r = 0; r < 4; r++)
          if (kc + ct * 16 + r > rowq) s[ct][r] = -1e30f;
    }

    // row max: in-register tree + 2 shuffles across the 4 hi-replicas
    f32x4 mm = fmax4(fmax4(s[0], s[1]), fmax4(s[2], s[3]));
    float tmx = fmaxf(fmaxf(mm[0], mm[1]), fmaxf(mm[2], mm[3]));
    tmx = fmaxf(tmx, __shfl_xor(tmx, 16));
    tmx = fmaxf(tmx, __shfl_xor(tmx, 32));
    float mn = fmaxf(mx, tmx);
    float al = __expf(mx - mn);
    mx = mn;
#pragma unroll
    for (int ct = 0; ct < 4; ct++)
#pragma unroll
      for (int r = 0; r < 4; r++) s[ct][r] = __expf(s[ct][r] - mn);
    f32x4 sm = s[0] + s[1] + s[2] + s[3];
    float rs = (sm[0] + sm[1]) + (sm[2] + sm[3]);
    rs += __shfl_xor(rs, 16);
    rs += __shfl_xor(rs, 32);
    ls = ls * al + rs;

    // P -> per-wave LDS (row l15, k-chunk ct*16+hi*4, XOR-swizzled, 8B writes)
#pragma unroll
    for (int ct = 0; ct < 4; ct++) {
      u16x4 pk = {f2bf(s[ct][0]), f2bf(s[ct][1]), f2bf(s[ct][2]), f2bf(s[ct][3])};
      *(u16x4*)(&ldsPw[(l15 * 128 + ((ct * 32 + hi * 8) ^ psw)) >> 1]) = pk;
    }

    // rescale ao (rows are q = hi*4+r): pull al from the owning lane
    float alr[4];
#pragma unroll
    for (int r = 0; r < 4; r++) alr[r] = __shfl(al, hi * 4 + r);
#pragma unroll
    for (int nt = 0; nt < 4; nt++)
#pragma unroll
      for (int r = 0; r < 4; r++) ao[nt][r] *= alr[r];

    // PV (per-wave ldsP: no barrier, same-wave DS ordering)
#pragma unroll
    for (int kk = 0; kk < 2; kk++) {
      bf16x8 pa = *(const bf16x8*)(&ldsPw[(l15 * 128 + ((kk * 64 + hi * 16) ^ psw)) >> 1]);
#pragma unroll
      for (int nt = 0; nt < 4; nt++) {
        int vrow = nt * 16 + l15;
        int c16 = (kk * 4 + hi) ^ (vrow & 7);
        bf16x8 vf = *(const bf16x8*)(&ldsV[cur][vrow * 64 + c16 * 8]);
        ao[nt] = mfma16(pa, vf, ao[nt]);
      }
    }
  }

  float snk = sinks[h];
  float lse = mx + __logf(ls);
  float ss = 1.f / (1.f + __expf(snk - lse));
  float f = ss / ls;
  float fr[4];
#pragma unroll
  for (int r = 0; r < 4; r++) fr[r] = __shfl(f, hi * 4 + r);
#pragma unroll
  for (int r = 0; r < 4; r++) {
    int row = q0 + hi * 4 + r;
#pragma unroll
    for (int nt = 0; nt < 4; nt++)
      Out[(size_t)row * (H * 64) + h * 64 + nt * 16 + l15] = f2bf(ao[nt][r] * fr[r]);
  }
}

extern "C" void kernel_launch(void* const* d_in, const int* in_sizes, int n_in,
                              void* d_out, int out_size, void* d_ws, size_t ws_size,
                              hipStream_t stream) {
  const int S = 1536, HID = 2880, H = 64, HKV = 8;
  const int NQ = 4096, NKV = 512, NQKV = 5120, NPAD = 2944;

  const float* x     = (const float*)d_in[0];
  const float* rope  = (const float*)d_in[1];
  const float* wq_w  = (const float*)d_in[2];
  const float* wq_b  = (const float*)d_in[3];
  const float* wk_w  = (const float*)d_in[4];
  const float* wk_b  = (const float*)d_in[5];
  const float* wv_w  = (const float*)d_in[6];
  const float* wv_b  = (const float*)d_in[7];
  const float* wo_w  = (const float*)d_in[8];
  const float* wo_b  = (const float*)d_in[9];
  const float* sinks = (const float*)d_in[10];
  float* out = (float*)d_out;

  char* ws = (char*)d_ws;
  size_t off = 0;
  auto alloc = [&](size_t bytes) {
    char* p = ws + off;
    off = (off + bytes + 255) & ~(size_t)255;
    return p;
  };
  u16*   x_bf    = (u16*)  alloc((size_t)S * HID * 2);
  u16*   wqkv_bf = (u16*)  alloc((size_t)NQKV * HID * 2);
  u16*   wo_bf   = (u16*)  alloc((size_t)NPAD * NQ * 2);
  float* qkv_raw = (float*)alloc((size_t)S * NQKV * 4);
  float* bias_p  = (float*)alloc((size_t)NQKV * 4);
  u16*   Qb      = (u16*)  alloc((size_t)H * S * 64 * 2);
  u16*   Kb      = (u16*)  alloc((size_t)HKV * S * 64 * 2);
  u16*   VTb     = (u16*)  alloc((size_t)HKV * 64 * S * 2);
  u16*   att     = (u16*)  alloc((size_t)S * NQ * 2);
  u16*   wq_bf = wqkv_bf;
  u16*   wk_bf = wqkv_bf + (size_t)NQ * HID;
  u16*   wv_bf = wqkv_bf + (size_t)(NQ + NKV) * HID;
  (void)ws_size; (void)n_in; (void)in_sizes; (void)out_size;

  auto cdiv = [](int a, int b) { return (a + b - 1) / b; };

  cvt_f2bf<<<cdiv(S * HID / 4, 256), 256, 0, stream>>>(x, x_bf, S * HID);
  cvt_f2bf<<<cdiv(NQ * HID / 4, 256), 256, 0, stream>>>(wq_w, wq_bf, NQ * HID);
  cvt_f2bf<<<cdiv(NKV * HID / 4, 256), 256, 0, stream>>>(wk_w, wk_bf, NKV * HID);
  cvt_f2bf<<<cdiv(NKV * HID / 4, 256), 256, 0, stream>>>(wv_w, wv_bf, NKV * HID);
  cvt_pad<<<cdiv(NPAD * NQ / 4, 256), 256, 0, stream>>>(wo_w, wo_bf, HID, NPAD, NQ);
  pack_bias<<<cdiv(NQKV, 256), 256, 0, stream>>>(wq_b, wk_b, wv_b, bias_p);

  gemm_bt<<<(S / 128) * (NQKV / 128), 256, 0, stream>>>(x_bf, wqkv_bf, bias_p, qkv_raw,
                                                        S, NQKV, HID, NQKV, NQKV);

  rope_tr<<<cdiv(S * NQ, 256), 256, 0, stream>>>(qkv_raw, rope, Qb, S, H, NQKV, 0, 0.125f);
  rope_tr<<<cdiv(S * NKV, 256), 256, 0, stream>>>(qkv_raw, rope, Kb, S, HKV, NQKV, NQ, 1.0f);
  cast_trT<<<dim3(S / 64, HKV), 256, 0, stream>>>(qkv_raw, VTb, S, HKV, NQKV, NQ + NKV);

  attn_fwd<<<dim3(S / 64, H), 256, 0, stream>>>(Qb, Kb, VTb, sinks, att, S, H, HKV);

  gemm_bt<<<(S / 128) * (NPAD / 128), 256, 0, stream>>>(att, wo_bf, wo_b, out,
                                                        S, NPAD, NQ, HID, HID);
}

// Round 4
// 253.313 us; speedup vs baseline: 2.1535x; 1.1831x over previous
//
#include <hip/hip_runtime.h>

typedef unsigned short u16;
typedef __attribute__((ext_vector_type(8))) __bf16 bf16x8;
typedef __attribute__((ext_vector_type(8))) u16 u16x8;
typedef __attribute__((ext_vector_type(4))) u16 u16x4;
typedef __attribute__((ext_vector_type(4))) float f32x4;

#define DEV static __device__ __forceinline__

DEV u16 f2bf(float f) {
  unsigned u = __builtin_bit_cast(unsigned, f);
  u += 0x7FFFu + ((u >> 16) & 1u);
  return (u16)(u >> 16);
}

DEV f32x4 mfma16(bf16x8 a, bf16x8 b, f32x4 c) {
  return __builtin_amdgcn_mfma_f32_16x16x32_bf16(a, b, c, 0, 0, 0);
}

DEV f32x4 fmax4(f32x4 a, f32x4 b) {
  f32x4 r;
  r[0] = fmaxf(a[0], b[0]); r[1] = fmaxf(a[1], b[1]);
  r[2] = fmaxf(a[2], b[2]); r[3] = fmaxf(a[3], b[3]);
  return r;
}

DEV void gload_lds16(const u16* g, u16* lds) {
  __builtin_amdgcn_global_load_lds(
      (const __attribute__((address_space(1))) void*)g,
      (__attribute__((address_space(3))) void*)lds, 16, 0, 0);
}

// ---- fp32 -> bf16 bulk convert (n % 4 == 0)
__global__ __launch_bounds__(256) void cvt_f2bf(const float* __restrict__ s,
                                                u16* __restrict__ d, int n) {
  int i = (blockIdx.x * 256 + threadIdx.x) * 4;
  if (i >= n) return;
  float4 v = *(const float4*)(s + i);
  u16x4 o = {f2bf(v.x), f2bf(v.y), f2bf(v.z), f2bf(v.w)};
  *(u16x4*)(d + i) = o;
}

// ---- wo_w (nrow_real x ncol) fp32 -> bf16, padded to nrow_pad rows (zeros)
__global__ __launch_bounds__(256) void cvt_pad(const float* __restrict__ s,
                                               u16* __restrict__ d,
                                               int nrow_real, int nrow_pad, int ncol) {
  int i = (blockIdx.x * 256 + threadIdx.x) * 4;
  if (i >= nrow_pad * ncol) return;
  int row = i / ncol;
  u16x4 o;
  if (row < nrow_real) {
    float4 v = *(const float4*)(s + i);
    o = (u16x4){f2bf(v.x), f2bf(v.y), f2bf(v.z), f2bf(v.w)};
  } else {
    o = (u16x4){0, 0, 0, 0};
  }
  *(u16x4*)(d + i) = o;
}

// ---- pack q/k/v biases into one [5120] vector
__global__ __launch_bounds__(256) void pack_bias(const float* __restrict__ q,
                                                 const float* __restrict__ k,
                                                 const float* __restrict__ v,
                                                 float* __restrict__ o) {
  int i = blockIdx.x * 256 + threadIdx.x;
  if (i >= 5120) return;
  o[i] = (i < 4096) ? q[i] : (i < 4608 ? k[i - 4096] : v[i - 4608]);
}

// ---- C[M][Nreal] = A[M][K] * B[N][K]^T + bias.  A,B bf16 (K-major), C fp32.
// 128x128 tile, BK=64, 4 waves. Double-buffered LDS prefetch (2-phase),
// XOR-swizzled LDS (pre-swizzled global source + swizzled ds_read),
// bn-major XCD-chunked block order (grid must be % 8 == 0).
__global__ __launch_bounds__(256) void gemm_bt(const u16* __restrict__ A,
                                               const u16* __restrict__ B,
                                               const float* __restrict__ bias,
                                               float* __restrict__ C,
                                               int M, int N, int K, int Nreal, int ldc) {
  __shared__ u16 smA[2][128 * 64];
  __shared__ u16 smB[2][128 * 64];
  int nbm = M >> 7;
  int chunk = gridDim.x >> 3;
  int wg = (blockIdx.x & 7) * chunk + (blockIdx.x >> 3);
  int bm = wg % nbm, bn = wg / nbm;
  int t = threadIdx.x, lane = t & 63, wv = t >> 6;
  int wr = wv >> 1, wc = wv & 1;
  int l15 = lane & 15, hi = lane >> 4;
  f32x4 acc[4][4] = {};
  // global source column pre-swizzled: LDS[row][c] holds global[row][c ^ (row&7)]
  int tr = t >> 3;
  int scol = ((t & 7) ^ (tr & 7)) * 8;
  const u16* Ab = A + (size_t)(bm * 128 + tr) * K + scol;
  const u16* Bb = B + (size_t)(bn * 128 + tr) * K + scol;

  auto stage = [&](int b, int ks) {
    int k0 = ks * 64;
#pragma unroll
    for (int i = 0; i < 4; i++) {
      gload_lds16(Ab + k0 + (size_t)i * 32 * K, &smA[b][i * 2048 + t * 8]);
      gload_lds16(Bb + k0 + (size_t)i * 32 * K, &smB[b][i * 2048 + t * 8]);
    }
  };

  int NK = K >> 6;
  stage(0, 0);
  for (int ks = 0; ks < NK; ks++) {
    int cur = ks & 1;
    __syncthreads();  // drains vmcnt: tile ks staged; prev readers of buf cur done
    if (ks + 1 < NK) stage(cur ^ 1, ks + 1);  // prefetch hides under compute
#pragma unroll
    for (int kk = 0; kk < 2; kk++) {
      int sc = ((kk * 4 + hi) ^ (l15 & 7)) * 8;
      bf16x8 af[4], bfr[4];
#pragma unroll
      for (int m = 0; m < 4; m++)
        af[m] = *(const bf16x8*)(&smA[cur][(wr * 64 + m * 16 + l15) * 64 + sc]);
#pragma unroll
      for (int n = 0; n < 4; n++)
        bfr[n] = *(const bf16x8*)(&smB[cur][(wc * 64 + n * 16 + l15) * 64 + sc]);
#pragma unroll
      for (int m = 0; m < 4; m++)
#pragma unroll
        for (int n = 0; n < 4; n++)
          acc[m][n] = mfma16(af[m], bfr[n], acc[m][n]);
    }
  }
  int r0 = bm * 128 + wr * 64 + hi * 4;
  int c0 = bn * 128 + wc * 64 + l15;
#pragma unroll
  for (int n = 0; n < 4; n++) {
    int col = c0 + n * 16;
    if (col >= Nreal) continue;
    float bv = bias[col];
#pragma unroll
    for (int m = 0; m < 4; m++) {
#pragma unroll
      for (int r = 0; r < 4; r++) {
        C[(size_t)(r0 + m * 16 + r) * ldc + col] = acc[m][n][r] + bv;
      }
    }
  }
}

// ---- src [S][ld] fp32 (cols col0..col0+H*64) -> dst [H][S][64] bf16, RoPE+scale
__global__ __launch_bounds__(256) void rope_tr(const float* __restrict__ src,
                                               const float* __restrict__ rope,
                                               u16* __restrict__ dst,
                                               int S, int H, int ld, int col0,
                                               float scale) {
  int i = blockIdx.x * 256 + threadIdx.x;
  if (i >= S * H * 64) return;
  int d = i & 63;
  int s = (i >> 6) % S;
  int h = i / (S * 64);
  const float* base = src + (size_t)s * ld + col0 + h * 64;
  float q = base[d];
  float qp = base[(d + 32) & 63];
  float c = rope[s * 128 + d];
  float sn = rope[s * 128 + 64 + d];
  float r = (d < 32) ? (q * c - qp * sn) : (q * c + qp * sn);
  dst[i] = f2bf(r * scale);
}

// ---- V transpose: src [S][ld] fp32 (cols col0+) -> dst [Hkv][64][S] bf16
__global__ __launch_bounds__(256) void cast_trT(const float* __restrict__ src,
                                                u16* __restrict__ dst, int S, int Hkv,
                                                int ld, int col0) {
  __shared__ u16 tile[64][65];
  int s0 = blockIdx.x * 64;
  int hkv = blockIdx.y;
  int t = threadIdx.x;
  int dl = (t & 15) * 4;
  int sl = t >> 4;
#pragma unroll
  for (int j = 0; j < 4; j++) {
    int s = sl + j * 16;
    float4 v = *(const float4*)(src + (size_t)(s0 + s) * ld + col0 + hkv * 64 + dl);
    tile[dl + 0][s] = f2bf(v.x);
    tile[dl + 1][s] = f2bf(v.y);
    tile[dl + 2][s] = f2bf(v.z);
    tile[dl + 3][s] = f2bf(v.w);
  }
  __syncthreads();
  int sl2 = (t & 7) * 8;
  int dl2 = t >> 3;
#pragma unroll
  for (int j = 0; j < 2; j++) {
    int d = dl2 + j * 32;
    u16x8 o;
#pragma unroll
    for (int c = 0; c < 8; c++) o[c] = tile[d][sl2 + c];
    *(u16x8*)(dst + ((size_t)hkv * 64 + d) * S + s0 + sl2) = o;
  }
}

// ---- flash attention fwd: block = (64 q-rows, 1 head), 4 waves x 16 rows.
// Swapped QK^T (mfma(K,Q)): each lane owns ONE q-row (l15) of scores ->
// in-register softmax reductions, only 2 shuffles per reduce.
// Q pre-scaled by 1/8. KV tiles of 64, double-buffered, XOR-swizzled LDS.
__global__ __launch_bounds__(256) void attn_fwd(const u16* __restrict__ Q,
                                                const u16* __restrict__ K,
                                                const u16* __restrict__ VT,
                                                const float* __restrict__ sinks,
                                                u16* __restrict__ Out,
                                                int S, int H, int Hkv) {
  __shared__ u16 ldsK[2][64 * 64];
  __shared__ u16 ldsV[2][64 * 64];  // V^T tile: [d][k]
  __shared__ u16 ldsP[4][16 * 64];
  int qb = gridDim.x - 1 - blockIdx.x;  // long blocks first
  int h = blockIdx.y;
  int hkv = h / (H / Hkv);
  int t = threadIdx.x, lane = t & 63, wv = t >> 6;
  int l15 = lane & 15, hi = lane >> 4;
  int q0 = qb * 64 + wv * 16;
  const u16* Qh = Q + ((size_t)h * S + q0) * 64;
  const u16* Kh = K + (size_t)hkv * S * 64;
  const u16* VTh = VT + (size_t)hkv * 64 * S;
  u16* ldsPw = &ldsP[wv][0];
  int psw = (l15 & 7) << 4;  // P swizzle for this lane's row

  bf16x8 qf[2];
  qf[0] = *(const bf16x8*)(Qh + l15 * 64 + hi * 8);
  qf[1] = *(const bf16x8*)(Qh + l15 * 64 + 32 + hi * 8);

  float mx = -1e30f, ls = 0.f;  // per-lane state for q-row (q0 + l15)
  f32x4 ao[4] = {};

  auto stage = [&](int b, int kb) {
    int k0 = kb * 64;
#pragma unroll
    for (int i = 0; i < 2; i++) {
      int c = i * 256 + t;
      int row = c >> 3, c16 = c & 7;
      int sc = (c16 ^ (row & 7)) * 8;
      gload_lds16(Kh + (size_t)(k0 + row) * 64 + sc, &ldsK[b][c * 8]);
      gload_lds16(VTh + (size_t)row * S + k0 + sc, &ldsV[b][c * 8]);
    }
  };

  int rowq = q0 + l15;
  stage(0, 0);
  for (int kb = 0; kb <= qb; kb++) {
    int cur = kb & 1;
    __syncthreads();  // tile kb staged; prev readers of buf cur^1 done
    if (kb < qb) stage(cur ^ 1, kb + 1);  // async prefetch under compute

    // QK^T swapped: s[ct][r] = score(q = q0+l15, k = kb*64 + ct*16 + hi*4 + r)
    f32x4 s[4] = {};
    __builtin_amdgcn_s_setprio(1);
#pragma unroll
    for (int kk = 0; kk < 2; kk++) {
#pragma unroll
      for (int ct = 0; ct < 4; ct++) {
        int row = ct * 16 + l15;
        int c16 = (kk * 4 + hi) ^ (row & 7);
        bf16x8 kf = *(const bf16x8*)(&ldsK[cur][row * 64 + c16 * 8]);
        s[ct] = mfma16(kf, qf[kk], s[ct]);
      }
    }
    __builtin_amdgcn_s_setprio(0);

    bool full = (kb * 64 + 63) < q0;  // wave-uniform: whole tile unmasked
    if (!full) {
      int kc = kb * 64 + hi * 4;
#pragma unroll
      for (int ct = 0; ct < 4; ct++)
#pragma unroll
        for (int r = 0; r < 4; r++)
          if (kc + ct * 16 + r > rowq) s[ct][r] = -1e30f;
    }

    // row max: in-register tree + 2 shuffles across the 4 hi-replicas
    f32x4 mm = fmax4(fmax4(s[0], s[1]), fmax4(s[2], s[3]));
    float tmx = fmaxf(fmaxf(mm[0], mm[1]), fmaxf(mm[2], mm[3]));
    tmx = fmaxf(tmx, __shfl_xor(tmx, 16));
    tmx = fmaxf(tmx, __shfl_xor(tmx, 32));
    float mn = fmaxf(mx, tmx);
    float al = __expf(mx - mn);
    mx = mn;
#pragma unroll
    for (int ct = 0; ct < 4; ct++)
#pragma unroll
      for (int r = 0; r < 4; r++) s[ct][r] = __expf(s[ct][r] - mn);
    f32x4 sm = s[0] + s[1] + s[2] + s[3];
    float rs = (sm[0] + sm[1]) + (sm[2] + sm[3]);
    rs += __shfl_xor(rs, 16);
    rs += __shfl_xor(rs, 32);
    ls = ls * al + rs;

    // P -> per-wave LDS (row l15, k-chunk ct*16+hi*4, XOR-swizzled, 8B writes)
#pragma unroll
    for (int ct = 0; ct < 4; ct++) {
      u16x4 pk = {f2bf(s[ct][0]), f2bf(s[ct][1]), f2bf(s[ct][2]), f2bf(s[ct][3])};
      *(u16x4*)(&ldsPw[(l15 * 128 + ((ct * 32 + hi * 8) ^ psw)) >> 1]) = pk;
    }

    // rescale ao (rows are q = hi*4+r): pull al from the owning lane
    float alr[4];
#pragma unroll
    for (int r = 0; r < 4; r++) alr[r] = __shfl(al, hi * 4 + r);
#pragma unroll
    for (int nt = 0; nt < 4; nt++)
#pragma unroll
      for (int r = 0; r < 4; r++) ao[nt][r] *= alr[r];

    // PV (per-wave ldsP: no barrier, same-wave DS ordering)
    __builtin_amdgcn_s_setprio(1);
#pragma unroll
    for (int kk = 0; kk < 2; kk++) {
      bf16x8 pa = *(const bf16x8*)(&ldsPw[(l15 * 128 + ((kk * 64 + hi * 16) ^ psw)) >> 1]);
#pragma unroll
      for (int nt = 0; nt < 4; nt++) {
        int vrow = nt * 16 + l15;
        int c16 = (kk * 4 + hi) ^ (vrow & 7);
        bf16x8 vf = *(const bf16x8*)(&ldsV[cur][vrow * 64 + c16 * 8]);
        ao[nt] = mfma16(pa, vf, ao[nt]);
      }
    }
    __builtin_amdgcn_s_setprio(0);
  }

  float snk = sinks[h];
  float lse = mx + __logf(ls);
  float ss = 1.f / (1.f + __expf(snk - lse));
  float f = ss / ls;
  float fr[4];
#pragma unroll
  for (int r = 0; r < 4; r++) fr[r] = __shfl(f, hi * 4 + r);
#pragma unroll
  for (int r = 0; r < 4; r++) {
    int row = q0 + hi * 4 + r;
#pragma unroll
    for (int nt = 0; nt < 4; nt++)
      Out[(size_t)row * (H * 64) + h * 64 + nt * 16 + l15] = f2bf(ao[nt][r] * fr[r]);
  }
}

extern "C" void kernel_launch(void* const* d_in, const int* in_sizes, int n_in,
                              void* d_out, int out_size, void* d_ws, size_t ws_size,
                              hipStream_t stream) {
  const int S = 1536, HID = 2880, H = 64, HKV = 8;
  const int NQ = 4096, NKV = 512, NQKV = 5120, NPAD = 3072;

  const float* x     = (const float*)d_in[0];
  const float* rope  = (const float*)d_in[1];
  const float* wq_w  = (const float*)d_in[2];
  const float* wq_b  = (const float*)d_in[3];
  const float* wk_w  = (const float*)d_in[4];
  const float* wk_b  = (const float*)d_in[5];
  const float* wv_w  = (const float*)d_in[6];
  const float* wv_b  = (const float*)d_in[7];
  const float* wo_w  = (const float*)d_in[8];
  const float* wo_b  = (const float*)d_in[9];
  const float* sinks = (const float*)d_in[10];
  float* out = (float*)d_out;

  char* ws = (char*)d_ws;
  size_t off = 0;
  auto alloc = [&](size_t bytes) {
    char* p = ws + off;
    off = (off + bytes + 255) & ~(size_t)255;
    return p;
  };
  u16*   x_bf    = (u16*)  alloc((size_t)S * HID * 2);
  u16*   wqkv_bf = (u16*)  alloc((size_t)NQKV * HID * 2);
  u16*   wo_bf   = (u16*)  alloc((size_t)NPAD * NQ * 2);
  float* qkv_raw = (float*)alloc((size_t)S * NQKV * 4);
  float* bias_p  = (float*)alloc((size_t)NQKV * 4);
  u16*   Qb      = (u16*)  alloc((size_t)H * S * 64 * 2);
  u16*   Kb      = (u16*)  alloc((size_t)HKV * S * 64 * 2);
  u16*   VTb     = (u16*)  alloc((size_t)HKV * 64 * S * 2);
  u16*   att     = (u16*)  alloc((size_t)S * NQ * 2);
  u16*   wq_bf = wqkv_bf;
  u16*   wk_bf = wqkv_bf + (size_t)NQ * HID;
  u16*   wv_bf = wqkv_bf + (size_t)(NQ + NKV) * HID;
  (void)ws_size; (void)n_in; (void)in_sizes; (void)out_size;

  auto cdiv = [](int a, int b) { return (a + b - 1) / b; };

  cvt_f2bf<<<cdiv(S * HID / 4, 256), 256, 0, stream>>>(x, x_bf, S * HID);
  cvt_f2bf<<<cdiv(NQ * HID / 4, 256), 256, 0, stream>>>(wq_w, wq_bf, NQ * HID);
  cvt_f2bf<<<cdiv(NKV * HID / 4, 256), 256, 0, stream>>>(wk_w, wk_bf, NKV * HID);
  cvt_f2bf<<<cdiv(NKV * HID / 4, 256), 256, 0, stream>>>(wv_w, wv_bf, NKV * HID);
  cvt_pad<<<cdiv(NPAD * NQ / 4, 256), 256, 0, stream>>>(wo_w, wo_bf, HID, NPAD, NQ);
  pack_bias<<<cdiv(NQKV, 256), 256, 0, stream>>>(wq_b, wk_b, wv_b, bias_p);

  gemm_bt<<<(S / 128) * (NQKV / 128), 256, 0, stream>>>(x_bf, wqkv_bf, bias_p, qkv_raw,
                                                        S, NQKV, HID, NQKV, NQKV);

  rope_tr<<<cdiv(S * NQ, 256), 256, 0, stream>>>(qkv_raw, rope, Qb, S, H, NQKV, 0, 0.125f);
  rope_tr<<<cdiv(S * NKV, 256), 256, 0, stream>>>(qkv_raw, rope, Kb, S, HKV, NQKV, NQ, 1.0f);
  cast_trT<<<dim3(S / 64, HKV), 256, 0, stream>>>(qkv_raw, VTb, S, HKV, NQKV, NQ + NKV);

  attn_fwd<<<dim3(S / 64, H), 256, 0, stream>>>(Qb, Kb, VTb, sinks, att, S, H, HKV);

  gemm_bt<<<(S / 128) * (NPAD / 128), 256, 0, stream>>>(att, wo_bf, wo_b, out,
                                                        S, NPAD, NQ, HID, HID);
}

// Round 6
// 236.305 us; speedup vs baseline: 2.3085x; 1.0720x over previous
//
#include <hip/hip_runtime.h>

typedef unsigned short u16;
typedef unsigned int u32;
typedef __attribute__((ext_vector_type(8))) __bf16 bf16x8;
typedef __attribute__((ext_vector_type(8))) u16 u16x8;
typedef __attribute__((ext_vector_type(4))) u16 u16x4;
typedef __attribute__((ext_vector_type(4))) float f32x4;
typedef __attribute__((ext_vector_type(2))) u32 u32x2;

#define DEV static __device__ __forceinline__

DEV u16 f2bf(float f) {
  unsigned u = __builtin_bit_cast(unsigned, f);
  u += 0x7FFFu + ((u >> 16) & 1u);
  return (u16)(u >> 16);
}

DEV float ex2(float x) { return __builtin_amdgcn_exp2f(x); }

DEV u32 cvt_pk_bf16(float lo, float hi) {
  u32 r;
  asm("v_cvt_pk_bf16_f32 %0, %1, %2" : "=v"(r) : "v"(lo), "v"(hi));
  return r;
}

DEV f32x4 mfma16(bf16x8 a, bf16x8 b, f32x4 c) {
  return __builtin_amdgcn_mfma_f32_16x16x32_bf16(a, b, c, 0, 0, 0);
}

DEV f32x4 fmax4(f32x4 a, f32x4 b) {
  f32x4 r;
  r[0] = fmaxf(a[0], b[0]); r[1] = fmaxf(a[1], b[1]);
  r[2] = fmaxf(a[2], b[2]); r[3] = fmaxf(a[3], b[3]);
  return r;
}

DEV void gload_lds16(const u16* g, u16* lds) {
  __builtin_amdgcn_global_load_lds(
      (const __attribute__((address_space(1))) void*)g,
      (__attribute__((address_space(3))) void*)lds, 16, 0, 0);
}

// ---- fp32 -> bf16 bulk convert (n % 4 == 0)
__global__ __launch_bounds__(256) void cvt_f2bf(const float* __restrict__ s,
                                                u16* __restrict__ d, int n) {
  int i = (blockIdx.x * 256 + threadIdx.x) * 4;
  if (i >= n) return;
  float4 v = *(const float4*)(s + i);
  u16x4 o = {f2bf(v.x), f2bf(v.y), f2bf(v.z), f2bf(v.w)};
  *(u16x4*)(d + i) = o;
}

// ---- wo_w (nrow_real x ncol) fp32 -> bf16, padded to nrow_pad rows (zeros)
__global__ __launch_bounds__(256) void cvt_pad(const float* __restrict__ s,
                                               u16* __restrict__ d,
                                               int nrow_real, int nrow_pad, int ncol) {
  int i = (blockIdx.x * 256 + threadIdx.x) * 4;
  if (i >= nrow_pad * ncol) return;
  int row = i / ncol;
  u16x4 o;
  if (row < nrow_real) {
    float4 v = *(const float4*)(s + i);
    o = (u16x4){f2bf(v.x), f2bf(v.y), f2bf(v.z), f2bf(v.w)};
  } else {
    o = (u16x4){0, 0, 0, 0};
  }
  *(u16x4*)(d + i) = o;
}

// ---- pack q/k/v biases into one [5120] vector
__global__ __launch_bounds__(256) void pack_bias(const float* __restrict__ q,
                                                 const float* __restrict__ k,
                                                 const float* __restrict__ v,
                                                 float* __restrict__ o) {
  int i = blockIdx.x * 256 + threadIdx.x;
  if (i >= 5120) return;
  o[i] = (i < 4096) ? q[i] : (i < 4608 ? k[i - 4096] : v[i - 4608]);
}

// ---- C[M][Nreal] = A[M][K] * B[N][K]^T + bias. 128x64 tile, BK=64, 4 waves.
// Double-buffered prefetch, XOR-swizzled LDS, bm-inner XCD-chunked order.
// grid = (M/128)*(N/64), must be % 8 == 0.
__global__ __launch_bounds__(256) void gemm_bt64(const u16* __restrict__ A,
                                                 const u16* __restrict__ B,
                                                 const float* __restrict__ bias,
                                                 float* __restrict__ C,
                                                 int M, int K, int Nreal, int ldc) {
  __shared__ u16 smA[2][128 * 64];
  __shared__ u16 smB[2][64 * 64];
  int nbm = M >> 7;
  int chunk = gridDim.x >> 3;
  int wg = (blockIdx.x & 7) * chunk + (blockIdx.x >> 3);
  int bm = wg % nbm, bn = wg / nbm;
  int t = threadIdx.x, lane = t & 63, wv = t >> 6;
  int l15 = lane & 15, hi = lane >> 4;
  f32x4 acc[2][4] = {};
  int tr = t >> 3;
  int scol = ((t & 7) ^ (tr & 7)) * 8;
  const u16* Ab = A + (size_t)(bm * 128 + tr) * K + scol;
  const u16* Bb = B + (size_t)(bn * 64 + tr) * K + scol;

  auto stage = [&](int b, int ks) {
    int k0 = ks * 64;
#pragma unroll
    for (int i = 0; i < 4; i++)
      gload_lds16(Ab + k0 + (size_t)i * 32 * K, &smA[b][i * 2048 + t * 8]);
#pragma unroll
    for (int i = 0; i < 2; i++)
      gload_lds16(Bb + k0 + (size_t)i * 32 * K, &smB[b][i * 2048 + t * 8]);
  };

  int NK = K >> 6;
  stage(0, 0);
  for (int ks = 0; ks < NK; ks++) {
    int cur = ks & 1;
    __syncthreads();  // tile ks staged; prev readers of buf cur done
    if (ks + 1 < NK) stage(cur ^ 1, ks + 1);  // prefetch hides under compute
#pragma unroll
    for (int kk = 0; kk < 2; kk++) {
      int sc = ((kk * 4 + hi) ^ (l15 & 7)) * 8;
      bf16x8 af[2], bfr[4];
#pragma unroll
      for (int m = 0; m < 2; m++)
        af[m] = *(const bf16x8*)(&smA[cur][(wv * 32 + m * 16 + l15) * 64 + sc]);
#pragma unroll
      for (int n = 0; n < 4; n++)
        bfr[n] = *(const bf16x8*)(&smB[cur][(n * 16 + l15) * 64 + sc]);
#pragma unroll
      for (int m = 0; m < 2; m++)
#pragma unroll
        for (int n = 0; n < 4; n++)
          acc[m][n] = mfma16(af[m], bfr[n], acc[m][n]);
    }
  }
  int r0 = bm * 128 + wv * 32 + hi * 4;
  int c0 = bn * 64 + l15;
#pragma unroll
  for (int n = 0; n < 4; n++) {
    int col = c0 + n * 16;
    if (col >= Nreal) continue;
    float bv = bias[col];
#pragma unroll
    for (int m = 0; m < 2; m++) {
#pragma unroll
      for (int r = 0; r < 4; r++) {
        C[(size_t)(r0 + m * 16 + r) * ldc + col] = acc[m][n][r] + bv;
      }
    }
  }
}

// ---- src [S][ld] fp32 (cols col0..col0+H*64) -> dst [H][S][64] bf16, RoPE+scale
__global__ __launch_bounds__(256) void rope_tr(const float* __restrict__ src,
                                               const float* __restrict__ rope,
                                               u16* __restrict__ dst,
                                               int S, int H, int ld, int col0,
                                               float scale) {
  int i = blockIdx.x * 256 + threadIdx.x;
  if (i >= S * H * 64) return;
  int d = i & 63;
  int s = (i >> 6) % S;
  int h = i / (S * 64);
  const float* base = src + (size_t)s * ld + col0 + h * 64;
  float q = base[d];
  float qp = base[(d + 32) & 63];
  float c = rope[s * 128 + d];
  float sn = rope[s * 128 + 64 + d];
  float r = (d < 32) ? (q * c - qp * sn) : (q * c + qp * sn);
  dst[i] = f2bf(r * scale);
}

// ---- V transpose: src [S][ld] fp32 (cols col0+) -> dst [Hkv][64][S] bf16
__global__ __launch_bounds__(256) void cast_trT(const float* __restrict__ src,
                                                u16* __restrict__ dst, int S, int Hkv,
                                                int ld, int col0) {
  __shared__ u16 tile[64][65];
  int s0 = blockIdx.x * 64;
  int hkv = blockIdx.y;
  int t = threadIdx.x;
  int dl = (t & 15) * 4;
  int sl = t >> 4;
#pragma unroll
  for (int j = 0; j < 4; j++) {
    int s = sl + j * 16;
    float4 v = *(const float4*)(src + (size_t)(s0 + s) * ld + col0 + hkv * 64 + dl);
    tile[dl + 0][s] = f2bf(v.x);
    tile[dl + 1][s] = f2bf(v.y);
    tile[dl + 2][s] = f2bf(v.z);
    tile[dl + 3][s] = f2bf(v.w);
  }
  __syncthreads();
  int sl2 = (t & 7) * 8;
  int dl2 = t >> 3;
#pragma unroll
  for (int j = 0; j < 2; j++) {
    int d = dl2 + j * 32;
    u16x8 o;
#pragma unroll
    for (int c = 0; c < 8; c++) o[c] = tile[d][sl2 + c];
    *(u16x8*)(dst + ((size_t)hkv * 64 + d) * S + s0 + sl2) = o;
  }
}

// ---- flash attention fwd: block = (128 q-rows, 1 head), 8 waves x 16 rows.
// Swapped QK^T (mfma(K,Q)): lane owns ONE q-row. log2-domain softmax
// (Q pre-scaled by 0.125*log2e), defer-max (THR=8 in log2), cvt_pk P-pack.
// KV tiles of 64, double-buffered, XOR-swizzled LDS.
__global__ __launch_bounds__(512) void attn_fwd(const u16* __restrict__ Q,
                                                const u16* __restrict__ K,
                                                const u16* __restrict__ VT,
                                                const float* __restrict__ sinks,
                                                u16* __restrict__ Out,
                                                int S, int H, int Hkv) {
  __shared__ u16 ldsK[2][64 * 64];
  __shared__ u16 ldsV[2][64 * 64];  // V^T tile: [d][k]
  __shared__ u16 ldsP[8][16 * 64];
  int qb = gridDim.x - 1 - blockIdx.x;  // long blocks first
  int h = blockIdx.y;
  int hkv = h / (H / Hkv);
  int t = threadIdx.x, lane = t & 63, wv = t >> 6;
  int l15 = lane & 15, hi = lane >> 4;
  int q0 = qb * 128 + wv * 16;
  const u16* Qh = Q + ((size_t)h * S + q0) * 64;
  const u16* Kh = K + (size_t)hkv * S * 64;
  const u16* VTh = VT + (size_t)hkv * 64 * S;
  u16* ldsPw = &ldsP[wv][0];
  int psw = (l15 & 7) << 4;  // P swizzle for this lane's row

  bf16x8 qf[2];
  qf[0] = *(const bf16x8*)(Qh + l15 * 64 + hi * 8);
  qf[1] = *(const bf16x8*)(Qh + l15 * 64 + 32 + hi * 8);

  float mx = -1e30f, ls = 0.f;  // per-lane state for q-row (q0 + l15), log2 units
  f32x4 ao[4] = {};

  auto stage = [&](int b, int kb) {
    int k0 = kb * 64;
    int row = t >> 3, c16 = t & 7;
    int sc = (c16 ^ (row & 7)) * 8;
    gload_lds16(Kh + (size_t)(k0 + row) * 64 + sc, &ldsK[b][t * 8]);
    gload_lds16(VTh + (size_t)row * S + k0 + sc, &ldsV[b][t * 8]);
  };

  int rowq = q0 + l15;
  int nkb = 2 * qb + 2;
  stage(0, 0);
  for (int kb = 0; kb < nkb; kb++) {
    int cur = kb & 1;
    __syncthreads();  // tile kb staged; prev readers of buf cur^1 done
    if (kb + 1 < nkb) stage(cur ^ 1, kb + 1);  // async prefetch under compute
    if (kb * 64 > q0 + 15) continue;  // wave-uniform: whole tile masked for wave

    // QK^T swapped: s[ct][r] = score(q = q0+l15, k = kb*64 + ct*16 + hi*4 + r)
    f32x4 s[4] = {};
    __builtin_amdgcn_s_setprio(1);
#pragma unroll
    for (int kk = 0; kk < 2; kk++) {
#pragma unroll
      for (int ct = 0; ct < 4; ct++) {
        int row = ct * 16 + l15;
        int c16 = (kk * 4 + hi) ^ (row & 7);
        bf16x8 kf = *(const bf16x8*)(&ldsK[cur][row * 64 + c16 * 8]);
        s[ct] = mfma16(kf, qf[kk], s[ct]);
      }
    }
    __builtin_amdgcn_s_setprio(0);

    bool full = (kb * 64 + 63) < q0;  // wave-uniform: whole tile unmasked
    if (!full) {
      int kc = kb * 64 + hi * 4;
#pragma unroll
      for (int ct = 0; ct < 4; ct++)
#pragma unroll
        for (int r = 0; r < 4; r++)
          if (kc + ct * 16 + r > rowq) s[ct][r] = -1e30f;
    }

    // row max: in-register tree + 2 shuffles across the 4 hi-replicas
    f32x4 mm = fmax4(fmax4(s[0], s[1]), fmax4(s[2], s[3]));
    float tmx = fmaxf(fmaxf(mm[0], mm[1]), fmaxf(mm[2], mm[3]));
    tmx = fmaxf(tmx, __shfl_xor(tmx, 16));
    tmx = fmaxf(tmx, __shfl_xor(tmx, 32));
    bool upd = __any(tmx > mx + 8.0f);  // defer-max: skip rescale if growth small
    if (upd) {
      float mn = fmaxf(mx, tmx);
      float al = ex2(mx - mn);
      mx = mn;
      ls *= al;
      float alr[4];
#pragma unroll
      for (int r = 0; r < 4; r++) alr[r] = __shfl(al, hi * 4 + r);
#pragma unroll
      for (int nt = 0; nt < 4; nt++)
#pragma unroll
        for (int r = 0; r < 4; r++) ao[nt][r] *= alr[r];
    }
#pragma unroll
    for (int ct = 0; ct < 4; ct++)
#pragma unroll
      for (int r = 0; r < 4; r++) s[ct][r] = ex2(s[ct][r] - mx);
    f32x4 sm = s[0] + s[1] + s[2] + s[3];
    float rs = (sm[0] + sm[1]) + (sm[2] + sm[3]);
    rs += __shfl_xor(rs, 16);
    rs += __shfl_xor(rs, 32);
    ls += rs;

    // P -> per-wave LDS (row l15, k-chunk ct*16+hi*4, XOR-swizzled, 8B writes)
#pragma unroll
    for (int ct = 0; ct < 4; ct++) {
      u32x2 pk = {cvt_pk_bf16(s[ct][0], s[ct][1]), cvt_pk_bf16(s[ct][2], s[ct][3])};
      *(u32x2*)(&ldsPw[(l15 * 128 + ((ct * 32 + hi * 8) ^ psw)) >> 1]) = pk;
    }

    // PV (per-wave ldsP: no barrier, same-wave DS ordering)
    __builtin_amdgcn_s_setprio(1);
#pragma unroll
    for (int kk = 0; kk < 2; kk++) {
      bf16x8 pa = *(const bf16x8*)(&ldsPw[(l15 * 128 + ((kk * 64 + hi * 16) ^ psw)) >> 1]);
#pragma unroll
      for (int nt = 0; nt < 4; nt++) {
        int vrow = nt * 16 + l15;
        int c16 = (kk * 4 + hi) ^ (vrow & 7);
        bf16x8 vf = *(const bf16x8*)(&ldsV[cur][vrow * 64 + c16 * 8]);
        ao[nt] = mfma16(pa, vf, ao[nt]);
      }
    }
    __builtin_amdgcn_s_setprio(0);
  }

  float snk = sinks[h];
  float lse = 0.69314718056f * mx + __logf(ls);  // back to natural log
  float ss = 1.f / (1.f + __expf(snk - lse));
  float f = ss / ls;
  float fr[4];
#pragma unroll
  for (int r = 0; r < 4; r++) fr[r] = __shfl(f, hi * 4 + r);
#pragma unroll
  for (int r = 0; r < 4; r++) {
    int row = q0 + hi * 4 + r;
#pragma unroll
    for (int nt = 0; nt < 4; nt++)
      Out[(size_t)row * (H * 64) + h * 64 + nt * 16 + l15] = f2bf(ao[nt][r] * fr[r]);
  }
}

extern "C" void kernel_launch(void* const* d_in, const int* in_sizes, int n_in,
                              void* d_out, int out_size, void* d_ws, size_t ws_size,
                              hipStream_t stream) {
  const int S = 1536, HID = 2880, H = 64, HKV = 8;
  const int NQ = 4096, NKV = 512, NQKV = 5120, NPAD = 2944;

  const float* x     = (const float*)d_in[0];
  const float* rope  = (const float*)d_in[1];
  const float* wq_w  = (const float*)d_in[2];
  const float* wq_b  = (const float*)d_in[3];
  const float* wk_w  = (const float*)d_in[4];
  const float* wk_b  = (const float*)d_in[5];
  const float* wv_w  = (const float*)d_in[6];
  const float* wv_b  = (const float*)d_in[7];
  const float* wo_w  = (const float*)d_in[8];
  const float* wo_b  = (const float*)d_in[9];
  const float* sinks = (const float*)d_in[10];
  float* out = (float*)d_out;

  char* ws = (char*)d_ws;
  size_t off = 0;
  auto alloc = [&](size_t bytes) {
    char* p = ws + off;
    off = (off + bytes + 255) & ~(size_t)255;
    return p;
  };
  u16*   x_bf    = (u16*)  alloc((size_t)S * HID * 2);
  u16*   wqkv_bf = (u16*)  alloc((size_t)NQKV * HID * 2);
  u16*   wo_bf   = (u16*)  alloc((size_t)NPAD * NQ * 2);
  float* qkv_raw = (float*)alloc((size_t)S * NQKV * 4);
  float* bias_p  = (float*)alloc((size_t)NQKV * 4);
  u16*   Qb      = (u16*)  alloc((size_t)H * S * 64 * 2);
  u16*   Kb      = (u16*)  alloc((size_t)HKV * S * 64 * 2);
  u16*   VTb     = (u16*)  alloc((size_t)HKV * 64 * S * 2);
  u16*   att     = (u16*)  alloc((size_t)S * NQ * 2);
  u16*   wq_bf = wqkv_bf;
  u16*   wk_bf = wqkv_bf + (size_t)NQ * HID;
  u16*   wv_bf = wqkv_bf + (size_t)(NQ + NKV) * HID;
  (void)ws_size; (void)n_in; (void)in_sizes; (void)out_size;

  auto cdiv = [](int a, int b) { return (a + b - 1) / b; };

  cvt_f2bf<<<cdiv(S * HID / 4, 256), 256, 0, stream>>>(x, x_bf, S * HID);
  cvt_f2bf<<<cdiv(NQ * HID / 4, 256), 256, 0, stream>>>(wq_w, wq_bf, NQ * HID);
  cvt_f2bf<<<cdiv(NKV * HID / 4, 256), 256, 0, stream>>>(wk_w, wk_bf, NKV * HID);
  cvt_f2bf<<<cdiv(NKV * HID / 4, 256), 256, 0, stream>>>(wv_w, wv_bf, NKV * HID);
  cvt_pad<<<cdiv(NPAD * NQ / 4, 256), 256, 0, stream>>>(wo_w, wo_bf, HID, NPAD, NQ);
  pack_bias<<<cdiv(NQKV, 256), 256, 0, stream>>>(wq_b, wk_b, wv_b, bias_p);

  // QKV fused projection: grid 12 * 80 = 960 (%8==0)
  gemm_bt64<<<(S / 128) * (NQKV / 64), 256, 0, stream>>>(x_bf, wqkv_bf, bias_p,
                                                         qkv_raw, S, HID, NQKV, NQKV);

  // Q pre-scaled by 1/8 * log2(e) for log2-domain softmax
  rope_tr<<<cdiv(S * NQ, 256), 256, 0, stream>>>(qkv_raw, rope, Qb, S, H, NQKV, 0,
                                                 0.125f * 1.44269504f);
  rope_tr<<<cdiv(S * NKV, 256), 256, 0, stream>>>(qkv_raw, rope, Kb, S, HKV, NQKV, NQ, 1.0f);
  cast_trT<<<dim3(S / 64, HKV), 256, 0, stream>>>(qkv_raw, VTb, S, HKV, NQKV, NQ + NKV);

  attn_fwd<<<dim3(S / 128, H), 512, 0, stream>>>(Qb, Kb, VTb, sinks, att, S, H, HKV);

  // wo projection: grid 12 * 46 = 552 (%8==0)
  gemm_bt64<<<(S / 128) * (NPAD / 64), 256, 0, stream>>>(att, wo_bf, wo_b, out,
                                                         S, NQ, HID, HID);
}

// Round 7
// 224.055 us; speedup vs baseline: 2.4347x; 1.0547x over previous
//
#include <hip/hip_runtime.h>

typedef unsigned short u16;
typedef unsigned int u32;
typedef __attribute__((ext_vector_type(8))) __bf16 bf16x8;
typedef __attribute__((ext_vector_type(8))) u16 u16x8;
typedef __attribute__((ext_vector_type(4))) u16 u16x4;
typedef __attribute__((ext_vector_type(4))) float f32x4;
typedef __attribute__((ext_vector_type(2))) u32 u32x2;

#define DEV static __device__ __forceinline__

DEV u16 f2bf(float f) {
  unsigned u = __builtin_bit_cast(unsigned, f);
  u += 0x7FFFu + ((u >> 16) & 1u);
  return (u16)(u >> 16);
}

DEV float ex2(float x) { return __builtin_amdgcn_exp2f(x); }

DEV u32 cvt_pk_bf16(float lo, float hi) {
  u32 r;
  asm("v_cvt_pk_bf16_f32 %0, %1, %2" : "=v"(r) : "v"(lo), "v"(hi));
  return r;
}

DEV f32x4 mfma16(bf16x8 a, bf16x8 b, f32x4 c) {
  return __builtin_amdgcn_mfma_f32_16x16x32_bf16(a, b, c, 0, 0, 0);
}

DEV f32x4 fmax4(f32x4 a, f32x4 b) {
  f32x4 r;
  r[0] = fmaxf(a[0], b[0]); r[1] = fmaxf(a[1], b[1]);
  r[2] = fmaxf(a[2], b[2]); r[3] = fmaxf(a[3], b[3]);
  return r;
}

DEV void gload_lds16(const u16* g, u16* lds) {
  __builtin_amdgcn_global_load_lds(
      (const __attribute__((address_space(1))) void*)g,
      (__attribute__((address_space(3))) void*)lds, 16, 0, 0);
}

DEV void vm_wait6() { asm volatile("s_waitcnt vmcnt(6)" ::: "memory"); }
DEV void vm_wait2() { asm volatile("s_waitcnt vmcnt(2)" ::: "memory"); }
DEV void vm_wait0() { asm volatile("s_waitcnt vmcnt(0)" ::: "memory"); }

// ---- one-shot convert: x, wq, wk, wv -> bf16; wo -> bf16 padded; bias pack
__global__ __launch_bounds__(256) void cvt_all(
    const float* __restrict__ x, const float* __restrict__ wq,
    const float* __restrict__ wk, const float* __restrict__ wv,
    const float* __restrict__ wo, const float* __restrict__ qb,
    const float* __restrict__ kb, const float* __restrict__ vb,
    u16* __restrict__ x_bf, u16* __restrict__ wqkv_bf,
    u16* __restrict__ wo_bf, float* __restrict__ bias_p) {
  const int NX = 1536 * 2880 / 4;        // x quads
  const int NWQ = 4096 * 2880 / 4;       // wq quads
  const int NWKV = 512 * 2880 / 4;       // wk / wv quads
  const int NWO = 2944 * 4096 / 4;       // wo padded quads
  const int C0 = NX, C1 = C0 + NWQ, C2 = C1 + NWKV, C3 = C2 + NWKV;
  const int C4 = C3 + NWO, C5 = C4 + 5120 / 4;
  int i = blockIdx.x * 256 + threadIdx.x;
  if (i >= C5) return;
  if (i < C4) {
    const float* s;
    u16* d;
    bool pad = false;
    if (i < C0) { s = x + (size_t)i * 4; d = x_bf + (size_t)i * 4; }
    else if (i < C1) { size_t q = i - C0; s = wq + q * 4; d = wqkv_bf + q * 4; }
    else if (i < C2) { size_t q = i - C1; s = wk + q * 4; d = wqkv_bf + (size_t)NWQ * 4 + q * 4; }
    else if (i < C3) { size_t q = i - C2; s = wv + q * 4; d = wqkv_bf + (size_t)(NWQ + NWKV) * 4 + q * 4; }
    else {
      size_t q = i - C3;
      int row = (int)(q >> 10);  // 4096/4 = 1024 quads per row
      pad = (row >= 2880);
      s = wo + q * 4; d = wo_bf + q * 4;
    }
    u16x4 o;
    if (!pad) {
      float4 v = *(const float4*)s;
      o = (u16x4){f2bf(v.x), f2bf(v.y), f2bf(v.z), f2bf(v.w)};
    } else {
      o = (u16x4){0, 0, 0, 0};
    }
    *(u16x4*)d = o;
  } else {
    int e = (i - C4) * 4;
#pragma unroll
    for (int j = 0; j < 4; j++) {
      int idx = e + j;
      bias_p[idx] = (idx < 4096) ? qb[idx] : (idx < 4608 ? kb[idx - 4096] : vb[idx - 4608]);
    }
  }
}

// ---- C[M][Nreal] = A[M][K] * B[N][K]^T + bias. 128x64 tile, BK=64, 4 waves.
// Counted-vmcnt 2-deep pipeline (no vmcnt(0) drain in main loop), XOR-swizzled
// LDS, bm-inner XCD-chunked order. grid = (M/128)*(N/64), % 8 == 0.
__global__ __launch_bounds__(256) void gemm_bt64(const u16* __restrict__ A,
                                                 const u16* __restrict__ B,
                                                 const float* __restrict__ bias,
                                                 float* __restrict__ C,
                                                 int M, int K, int Nreal, int ldc) {
  __shared__ u16 smA[2][128 * 64];
  __shared__ u16 smB[2][64 * 64];
  int nbm = M >> 7;
  int chunk = gridDim.x >> 3;
  int wg = (blockIdx.x & 7) * chunk + (blockIdx.x >> 3);
  int bm = wg % nbm, bn = wg / nbm;
  int t = threadIdx.x, lane = t & 63;
  int wv = t >> 6;
  int l15 = lane & 15, hi = lane >> 4;
  f32x4 acc[2][4] = {};
  int tr = t >> 3;
  int scol = ((t & 7) ^ (tr & 7)) * 8;
  const u16* Ab = A + (size_t)(bm * 128 + tr) * K + scol;
  const u16* Bb = B + (size_t)(bn * 64 + tr) * K + scol;

  auto stage = [&](int b, int ks) {  // 6 loads / thread
    int k0 = ks * 64;
#pragma unroll
    for (int i = 0; i < 4; i++)
      gload_lds16(Ab + k0 + (size_t)i * 32 * K, &smA[b][i * 2048 + t * 8]);
#pragma unroll
    for (int i = 0; i < 2; i++)
      gload_lds16(Bb + k0 + (size_t)i * 32 * K, &smB[b][i * 2048 + t * 8]);
  };

  int NK = K >> 6;
  stage(0, 0);
  if (NK > 1) stage(1, 1);
  for (int ks = 0; ks < NK; ks++) {
    int cur = ks & 1;
    if (ks + 1 < NK) vm_wait6(); else vm_wait0();  // tile ks complete (own loads)
    __builtin_amdgcn_s_barrier();                  // all waves: tile ks in LDS
    __builtin_amdgcn_sched_barrier(0);
#pragma unroll
    for (int kk = 0; kk < 2; kk++) {
      int sc = ((kk * 4 + hi) ^ (l15 & 7)) * 8;
      bf16x8 af[2], bfr[4];
#pragma unroll
      for (int m = 0; m < 2; m++)
        af[m] = *(const bf16x8*)(&smA[cur][(wv * 32 + m * 16 + l15) * 64 + sc]);
#pragma unroll
      for (int n = 0; n < 4; n++)
        bfr[n] = *(const bf16x8*)(&smB[cur][(n * 16 + l15) * 64 + sc]);
      __builtin_amdgcn_s_setprio(1);
#pragma unroll
      for (int m = 0; m < 2; m++)
#pragma unroll
        for (int n = 0; n < 4; n++)
          acc[m][n] = mfma16(af[m], bfr[n], acc[m][n]);
      __builtin_amdgcn_s_setprio(0);
    }
    __builtin_amdgcn_s_barrier();        // all waves done reading buf cur
    if (ks + 2 < NK) stage(cur, ks + 2); // refill freed buffer, spans next iter
  }
  int r0 = bm * 128 + wv * 32 + hi * 4;
  int c0 = bn * 64 + l15;
#pragma unroll
  for (int n = 0; n < 4; n++) {
    int col = c0 + n * 16;
    if (col >= Nreal) continue;
    float bv = bias[col];
#pragma unroll
    for (int m = 0; m < 2; m++) {
#pragma unroll
      for (int r = 0; r < 4; r++) {
        C[(size_t)(r0 + m * 16 + r) * ldc + col] = acc[m][n][r] + bv;
      }
    }
  }
}

// ---- src [S][ld] fp32 (cols col0..col0+H*64) -> dst [H][S][64] bf16, RoPE+scale
__global__ __launch_bounds__(256) void rope_tr(const float* __restrict__ src,
                                               const float* __restrict__ rope,
                                               u16* __restrict__ dst,
                                               int S, int H, int ld, int col0,
                                               float scale) {
  int i = blockIdx.x * 256 + threadIdx.x;
  if (i >= S * H * 64) return;
  int d = i & 63;
  int s = (i >> 6) % S;
  int h = i / (S * 64);
  const float* base = src + (size_t)s * ld + col0 + h * 64;
  float q = base[d];
  float qp = base[(d + 32) & 63];
  float c = rope[s * 128 + d];
  float sn = rope[s * 128 + 64 + d];
  float r = (d < 32) ? (q * c - qp * sn) : (q * c + qp * sn);
  dst[i] = f2bf(r * scale);
}

// ---- V transpose: src [S][ld] fp32 (cols col0+) -> dst [Hkv][64][S] bf16
__global__ __launch_bounds__(256) void cast_trT(const float* __restrict__ src,
                                                u16* __restrict__ dst, int S, int Hkv,
                                                int ld, int col0) {
  __shared__ u16 tile[64][65];
  int s0 = blockIdx.x * 64;
  int hkv = blockIdx.y;
  int t = threadIdx.x;
  int dl = (t & 15) * 4;
  int sl = t >> 4;
#pragma unroll
  for (int j = 0; j < 4; j++) {
    int s = sl + j * 16;
    float4 v = *(const float4*)(src + (size_t)(s0 + s) * ld + col0 + hkv * 64 + dl);
    tile[dl + 0][s] = f2bf(v.x);
    tile[dl + 1][s] = f2bf(v.y);
    tile[dl + 2][s] = f2bf(v.z);
    tile[dl + 3][s] = f2bf(v.w);
  }
  __syncthreads();
  int sl2 = (t & 7) * 8;
  int dl2 = t >> 3;
#pragma unroll
  for (int j = 0; j < 2; j++) {
    int d = dl2 + j * 32;
    u16x8 o;
#pragma unroll
    for (int c = 0; c < 8; c++) o[c] = tile[d][sl2 + c];
    *(u16x8*)(dst + ((size_t)hkv * 64 + d) * S + s0 + sl2) = o;
  }
}

// ---- flash attention fwd: block = (128 q-rows, 1 head), 8 waves x 16 rows.
// Swapped QK^T (mfma(K,Q)): lane owns ONE q-row. log2-domain softmax
// (Q pre-scaled by 0.125*log2e), defer-max, cvt_pk P-pack.
// KV tiles of 64, counted-vmcnt 2-deep pipeline, XOR-swizzled LDS.
__global__ __launch_bounds__(512) void attn_fwd(const u16* __restrict__ Q,
                                                const u16* __restrict__ K,
                                                const u16* __restrict__ VT,
                                                const float* __restrict__ sinks,
                                                u16* __restrict__ Out,
                                                int S, int H, int Hkv) {
  __shared__ u16 ldsK[2][64 * 64];
  __shared__ u16 ldsV[2][64 * 64];  // V^T tile: [d][k]
  __shared__ u16 ldsP[8][16 * 64];
  int qb = gridDim.x - 1 - blockIdx.x;  // long blocks first
  int h = blockIdx.y;
  int hkv = h / (H / Hkv);
  int t = threadIdx.x, lane = t & 63, wv = t >> 6;
  int l15 = lane & 15, hi = lane >> 4;
  int q0 = qb * 128 + wv * 16;
  const u16* Qh = Q + ((size_t)h * S + q0) * 64;
  const u16* Kh = K + (size_t)hkv * S * 64;
  const u16* VTh = VT + (size_t)hkv * 64 * S;
  u16* ldsPw = &ldsP[wv][0];
  int psw = (l15 & 7) << 4;  // P swizzle for this lane's row

  bf16x8 qf[2];
  qf[0] = *(const bf16x8*)(Qh + l15 * 64 + hi * 8);
  qf[1] = *(const bf16x8*)(Qh + l15 * 64 + 32 + hi * 8);

  float mx = -1e30f, ls = 0.f;  // per-lane state for q-row (q0 + l15), log2 units
  f32x4 ao[4] = {};

  auto stage = [&](int b, int kb) {  // 2 loads / thread
    int k0 = kb * 64;
    int row = t >> 3, c16 = t & 7;
    int sc = (c16 ^ (row & 7)) * 8;
    gload_lds16(Kh + (size_t)(k0 + row) * 64 + sc, &ldsK[b][t * 8]);
    gload_lds16(VTh + (size_t)row * S + k0 + sc, &ldsV[b][t * 8]);
  };

  int rowq = q0 + l15;
  int nkb = 2 * qb + 2;
  stage(0, 0);
  stage(1, 1);
  for (int kb = 0; kb < nkb; kb++) {
    int cur = kb & 1;
    if (kb + 1 < nkb) vm_wait2(); else vm_wait0();  // tile kb complete
    __builtin_amdgcn_s_barrier();
    __builtin_amdgcn_sched_barrier(0);
    if (kb * 64 <= q0 + 15) {  // wave-uniform: any unmasked cols in tile?
      // QK^T swapped: s[ct][r] = score(q = q0+l15, k = kb*64 + ct*16 + hi*4 + r)
      f32x4 s[4] = {};
      __builtin_amdgcn_s_setprio(1);
#pragma unroll
      for (int kk = 0; kk < 2; kk++) {
#pragma unroll
        for (int ct = 0; ct < 4; ct++) {
          int row = ct * 16 + l15;
          int c16 = (kk * 4 + hi) ^ (row & 7);
          bf16x8 kf = *(const bf16x8*)(&ldsK[cur][row * 64 + c16 * 8]);
          s[ct] = mfma16(kf, qf[kk], s[ct]);
        }
      }
      __builtin_amdgcn_s_setprio(0);

      bool full = (kb * 64 + 63) < q0;  // wave-uniform: whole tile unmasked
      if (!full) {
        int kc = kb * 64 + hi * 4;
#pragma unroll
        for (int ct = 0; ct < 4; ct++)
#pragma unroll
          for (int r = 0; r < 4; r++)
            if (kc + ct * 16 + r > rowq) s[ct][r] = -1e30f;
      }

      // row max: in-register tree + 2 shuffles across the 4 hi-replicas
      f32x4 mm = fmax4(fmax4(s[0], s[1]), fmax4(s[2], s[3]));
      float tmx = fmaxf(fmaxf(mm[0], mm[1]), fmaxf(mm[2], mm[3]));
      tmx = fmaxf(tmx, __shfl_xor(tmx, 16));
      tmx = fmaxf(tmx, __shfl_xor(tmx, 32));
      bool upd = __any(tmx > mx + 8.0f);  // defer-max
      if (upd) {
        float mn = fmaxf(mx, tmx);
        float al = ex2(mx - mn);
        mx = mn;
        ls *= al;
        float alr[4];
#pragma unroll
        for (int r = 0; r < 4; r++) alr[r] = __shfl(al, hi * 4 + r);
#pragma unroll
        for (int nt = 0; nt < 4; nt++)
#pragma unroll
          for (int r = 0; r < 4; r++) ao[nt][r] *= alr[r];
      }
#pragma unroll
      for (int ct = 0; ct < 4; ct++)
#pragma unroll
        for (int r = 0; r < 4; r++) s[ct][r] = ex2(s[ct][r] - mx);
      f32x4 sm = s[0] + s[1] + s[2] + s[3];
      float rs = (sm[0] + sm[1]) + (sm[2] + sm[3]);
      rs += __shfl_xor(rs, 16);
      rs += __shfl_xor(rs, 32);
      ls += rs;

      // P -> per-wave LDS (row l15, k-chunk ct*16+hi*4, XOR-swizzled, 8B writes)
#pragma unroll
      for (int ct = 0; ct < 4; ct++) {
        u32x2 pk = {cvt_pk_bf16(s[ct][0], s[ct][1]), cvt_pk_bf16(s[ct][2], s[ct][3])};
        *(u32x2*)(&ldsPw[(l15 * 128 + ((ct * 32 + hi * 8) ^ psw)) >> 1]) = pk;
      }

      // PV (per-wave ldsP: no barrier, same-wave DS ordering)
      __builtin_amdgcn_s_setprio(1);
#pragma unroll
      for (int kk = 0; kk < 2; kk++) {
        bf16x8 pa = *(const bf16x8*)(&ldsPw[(l15 * 128 + ((kk * 64 + hi * 16) ^ psw)) >> 1]);
#pragma unroll
        for (int nt = 0; nt < 4; nt++) {
          int vrow = nt * 16 + l15;
          int c16 = (kk * 4 + hi) ^ (vrow & 7);
          bf16x8 vf = *(const bf16x8*)(&ldsV[cur][vrow * 64 + c16 * 8]);
          ao[nt] = mfma16(pa, vf, ao[nt]);
        }
      }
      __builtin_amdgcn_s_setprio(0);
    }
    __builtin_amdgcn_s_barrier();          // all waves done with buf cur
    if (kb + 2 < nkb) stage(cur, kb + 2);  // refill freed buffer
  }

  float snk = sinks[h];
  float lse = 0.69314718056f * mx + __logf(ls);  // back to natural log
  float ss = 1.f / (1.f + __expf(snk - lse));
  float f = ss / ls;
  float fr[4];
#pragma unroll
  for (int r = 0; r < 4; r++) fr[r] = __shfl(f, hi * 4 + r);
#pragma unroll
  for (int r = 0; r < 4; r++) {
    int row = q0 + hi * 4 + r;
#pragma unroll
    for (int nt = 0; nt < 4; nt++)
      Out[(size_t)row * (H * 64) + h * 64 + nt * 16 + l15] = f2bf(ao[nt][r] * fr[r]);
  }
}

extern "C" void kernel_launch(void* const* d_in, const int* in_sizes, int n_in,
                              void* d_out, int out_size, void* d_ws, size_t ws_size,
                              hipStream_t stream) {
  const int S = 1536, HID = 2880, H = 64, HKV = 8;
  const int NQ = 4096, NKV = 512, NQKV = 5120, NPAD = 2944;

  const float* x     = (const float*)d_in[0];
  const float* rope  = (const float*)d_in[1];
  const float* wq_w  = (const float*)d_in[2];
  const float* wq_b  = (const float*)d_in[3];
  const float* wk_w  = (const float*)d_in[4];
  const float* wk_b  = (const float*)d_in[5];
  const float* wv_w  = (const float*)d_in[6];
  const float* wv_b  = (const float*)d_in[7];
  const float* wo_w  = (const float*)d_in[8];
  const float* wo_b  = (const float*)d_in[9];
  const float* sinks = (const float*)d_in[10];
  float* out = (float*)d_out;

  char* ws = (char*)d_ws;
  size_t off = 0;
  auto alloc = [&](size_t bytes) {
    char* p = ws + off;
    off = (off + bytes + 255) & ~(size_t)255;
    return p;
  };
  u16*   x_bf    = (u16*)  alloc((size_t)S * HID * 2);
  u16*   wqkv_bf = (u16*)  alloc((size_t)NQKV * HID * 2);
  u16*   wo_bf   = (u16*)  alloc((size_t)NPAD * NQ * 2);
  float* qkv_raw = (float*)alloc((size_t)S * NQKV * 4);
  float* bias_p  = (float*)alloc((size_t)NQKV * 4);
  u16*   Qb      = (u16*)  alloc((size_t)H * S * 64 * 2);
  u16*   Kb      = (u16*)  alloc((size_t)HKV * S * 64 * 2);
  u16*   VTb     = (u16*)  alloc((size_t)HKV * 64 * S * 2);
  u16*   att     = (u16*)  alloc((size_t)S * NQ * 2);
  (void)ws_size; (void)n_in; (void)in_sizes; (void)out_size;

  auto cdiv = [](int a, int b) { return (a + b - 1) / b; };

  // total convert quads: see cvt_all (x, wq, wk, wv, wo_pad, bias)
  const int NCVT = S * HID / 4 + NQ * HID / 4 + 2 * (NKV * HID / 4) +
                   NPAD * NQ / 4 + NQKV / 4;
  cvt_all<<<cdiv(NCVT, 256), 256, 0, stream>>>(x, wq_w, wk_w, wv_w, wo_w,
                                               wq_b, wk_b, wv_b,
                                               x_bf, wqkv_bf, wo_bf, bias_p);

  // QKV fused projection: grid 12 * 80 = 960 (%8==0)
  gemm_bt64<<<(S / 128) * (NQKV / 64), 256, 0, stream>>>(x_bf, wqkv_bf, bias_p,
                                                         qkv_raw, S, HID, NQKV, NQKV);

  // Q pre-scaled by 1/8 * log2(e) for log2-domain softmax
  rope_tr<<<cdiv(S * NQ, 256), 256, 0, stream>>>(qkv_raw, rope, Qb, S, H, NQKV, 0,
                                                 0.125f * 1.44269504f);
  rope_tr<<<cdiv(S * NKV, 256), 256, 0, stream>>>(qkv_raw, rope, Kb, S, HKV, NQKV, NQ, 1.0f);
  cast_trT<<<dim3(S / 64, HKV), 256, 0, stream>>>(qkv_raw, VTb, S, HKV, NQKV, NQ + NKV);

  attn_fwd<<<dim3(S / 128, H), 512, 0, stream>>>(Qb, Kb, VTb, sinks, att, S, H, HKV);

  // wo projection: grid 12 * 46 = 552 (%8==0)
  gemm_bt64<<<(S / 128) * (NPAD / 64), 256, 0, stream>>>(att, wo_bf, wo_b, out,
                                                         S, NQ, HID, HID);
}

// Round 8
// 203.094 us; speedup vs baseline: 2.6860x; 1.1032x over previous
//
#include <hip/hip_runtime.h>

typedef unsigned short u16;
typedef unsigned int u32;
typedef __attribute__((ext_vector_type(8))) __bf16 bf16x8;
typedef __attribute__((ext_vector_type(8))) u16 u16x8;
typedef __attribute__((ext_vector_type(4))) u16 u16x4;
typedef __attribute__((ext_vector_type(4))) float f32x4;
typedef __attribute__((ext_vector_type(2))) u32 u32x2;

#define DEV static __device__ __forceinline__

DEV u16 f2bf(float f) {
  unsigned u = __builtin_bit_cast(unsigned, f);
  u += 0x7FFFu + ((u >> 16) & 1u);
  return (u16)(u >> 16);
}

DEV float ex2(float x) { return __builtin_amdgcn_exp2f(x); }

DEV u32 cvt_pk_bf16(float lo, float hi) {
  u32 r;
  asm("v_cvt_pk_bf16_f32 %0, %1, %2" : "=v"(r) : "v"(lo), "v"(hi));
  return r;
}

DEV f32x4 mfma16(bf16x8 a, bf16x8 b, f32x4 c) {
  return __builtin_amdgcn_mfma_f32_16x16x32_bf16(a, b, c, 0, 0, 0);
}

DEV f32x4 fmax4(f32x4 a, f32x4 b) {
  f32x4 r;
  r[0] = fmaxf(a[0], b[0]); r[1] = fmaxf(a[1], b[1]);
  r[2] = fmaxf(a[2], b[2]); r[3] = fmaxf(a[3], b[3]);
  return r;
}

DEV void gload_lds16(const u16* g, u16* lds) {
  __builtin_amdgcn_global_load_lds(
      (const __attribute__((address_space(1))) void*)g,
      (__attribute__((address_space(3))) void*)lds, 16, 0, 0);
}

DEV void vm_wait4() { asm volatile("s_waitcnt vmcnt(4)" ::: "memory"); }
DEV void vm_wait2() { asm volatile("s_waitcnt vmcnt(2)" ::: "memory"); }
DEV void vm_wait0() { asm volatile("s_waitcnt vmcnt(0)" ::: "memory"); }

// ---- one-shot convert: x, wq, wk, wv -> bf16; wo -> bf16 padded; bias pack
__global__ __launch_bounds__(256) void cvt_all(
    const float* __restrict__ x, const float* __restrict__ wq,
    const float* __restrict__ wk, const float* __restrict__ wv,
    const float* __restrict__ wo, const float* __restrict__ qb,
    const float* __restrict__ kb, const float* __restrict__ vb,
    u16* __restrict__ x_bf, u16* __restrict__ wqkv_bf,
    u16* __restrict__ wo_bf, float* __restrict__ bias_p) {
  const int NX = 1536 * 2880 / 4;        // x quads
  const int NWQ = 4096 * 2880 / 4;       // wq quads
  const int NWKV = 512 * 2880 / 4;       // wk / wv quads
  const int NWO = 3072 * 4096 / 4;       // wo padded quads
  const int C0 = NX, C1 = C0 + NWQ, C2 = C1 + NWKV, C3 = C2 + NWKV;
  const int C4 = C3 + NWO, C5 = C4 + 5120 / 4;
  int i = blockIdx.x * 256 + threadIdx.x;
  if (i >= C5) return;
  if (i < C4) {
    const float* s;
    u16* d;
    bool pad = false;
    if (i < C0) { s = x + (size_t)i * 4; d = x_bf + (size_t)i * 4; }
    else if (i < C1) { size_t q = i - C0; s = wq + q * 4; d = wqkv_bf + q * 4; }
    else if (i < C2) { size_t q = i - C1; s = wk + q * 4; d = wqkv_bf + (size_t)NWQ * 4 + q * 4; }
    else if (i < C3) { size_t q = i - C2; s = wv + q * 4; d = wqkv_bf + (size_t)(NWQ + NWKV) * 4 + q * 4; }
    else {
      size_t q = i - C3;
      int row = (int)(q >> 10);  // 4096/4 = 1024 quads per row
      pad = (row >= 2880);
      s = wo + q * 4; d = wo_bf + q * 4;
    }
    u16x4 o;
    if (!pad) {
      float4 v = *(const float4*)s;
      o = (u16x4){f2bf(v.x), f2bf(v.y), f2bf(v.z), f2bf(v.w)};
    } else {
      o = (u16x4){0, 0, 0, 0};
    }
    *(u16x4*)d = o;
  } else {
    int e = (i - C4) * 4;
#pragma unroll
    for (int j = 0; j < 4; j++) {
      int idx = e + j;
      bias_p[idx] = (idx < 4096) ? qb[idx] : (idx < 4608 ? kb[idx - 4096] : vb[idx - 4608]);
    }
  }
}

// ---- 128x128 tile GEMM, BK=64, 8 waves (4x2), counted-vmcnt 2-deep pipeline,
// XOR-swizzled LDS, bm-inner XCD-chunked order. grid %8 == 0.
// MODE 0: C fp32 = A*B^T + bias (cols < Nreal).
// MODE 1: QKV epilogue -> Obf[S][5120] bf16 with bias + RoPE(Q,K) + Q-scale.
template <int MODE>
__global__ __launch_bounds__(512) void gemm128(const u16* __restrict__ A,
                                               const u16* __restrict__ B,
                                               const float* __restrict__ bias,
                                               float* __restrict__ C,
                                               u16* __restrict__ Obf,
                                               const float* __restrict__ rope,
                                               int M, int K, int Nreal, int ldc) {
  __shared__ u16 smA[2][128 * 64];
  __shared__ u16 smB[2][128 * 64];
  int nbm = M >> 7;
  int chunk = gridDim.x >> 3;
  int wg = (blockIdx.x & 7) * chunk + (blockIdx.x >> 3);
  int bm = wg % nbm, bn = wg / nbm;
  int t = threadIdx.x, lane = t & 63, wv = t >> 6;
  int wr = wv >> 1, wc = wv & 1;  // 4x2 wave grid; wave tile 32 rows x 64 cols
  int l15 = lane & 15, hi = lane >> 4;
  f32x4 acc[2][4] = {};
  int tr = t >> 3;
  int scol = ((t & 7) ^ (tr & 7)) * 8;
  const u16* Ab = A + (size_t)(bm * 128 + tr) * K + scol;
  const u16* Bb = B + (size_t)(bn * 128 + tr) * K + scol;

  auto stage = [&](int b, int ks) {  // 4 loads / thread
    int k0 = ks * 64;
    gload_lds16(Ab + k0, &smA[b][t * 8]);
    gload_lds16(Ab + k0 + (size_t)64 * K, &smA[b][4096 + t * 8]);
    gload_lds16(Bb + k0, &smB[b][t * 8]);
    gload_lds16(Bb + k0 + (size_t)64 * K, &smB[b][4096 + t * 8]);
  };

  int NK = K >> 6;
  stage(0, 0);
  stage(1, 1);
  for (int ks = 0; ks < NK; ks++) {
    int cur = ks & 1;
    if (ks + 1 < NK) vm_wait4(); else vm_wait0();  // tile ks complete
    __builtin_amdgcn_s_barrier();
    __builtin_amdgcn_sched_barrier(0);
#pragma unroll
    for (int kk = 0; kk < 2; kk++) {
      int sc = ((kk * 4 + hi) ^ (l15 & 7)) * 8;
      bf16x8 af[2], bfr[4];
#pragma unroll
      for (int m = 0; m < 2; m++)
        af[m] = *(const bf16x8*)(&smA[cur][(wr * 32 + m * 16 + l15) * 64 + sc]);
#pragma unroll
      for (int n = 0; n < 4; n++)
        bfr[n] = *(const bf16x8*)(&smB[cur][(wc * 64 + n * 16 + l15) * 64 + sc]);
      __builtin_amdgcn_s_setprio(1);
#pragma unroll
      for (int m = 0; m < 2; m++)
#pragma unroll
        for (int n = 0; n < 4; n++)
          acc[m][n] = mfma16(af[m], bfr[n], acc[m][n]);
      __builtin_amdgcn_s_setprio(0);
    }
    __builtin_amdgcn_s_barrier();        // all waves done reading buf cur
    if (ks + 2 < NK) stage(cur, ks + 2); // refill freed buffer
  }

  int r0 = bm * 128 + wr * 32 + hi * 4;
  int c0 = bn * 128 + wc * 64 + l15;
  if (MODE == 0) {
#pragma unroll
    for (int n = 0; n < 4; n++) {
      int col = c0 + n * 16;
      if (col >= Nreal) continue;
      float bv = bias[col];
#pragma unroll
      for (int m = 0; m < 2; m++)
#pragma unroll
        for (int r = 0; r < 4; r++)
          C[(size_t)(r0 + m * 16 + r) * ldc + col] = acc[m][n][r] + bv;
    }
  } else {
    float bv[4];
#pragma unroll
    for (int n = 0; n < 4; n++) bv[n] = bias[c0 + n * 16];
    if (bn < 36) {  // Q or K head: RoPE (head = 64 cols = one wave tile)
      float scale = (bn < 32) ? 0.180336880f : 1.0f;  // Q: 0.125*log2(e)
#pragma unroll
      for (int m = 0; m < 2; m++) {
#pragma unroll
        for (int r = 0; r < 4; r++) {
          int s = r0 + m * 16 + r;
          const float* rp = rope + (size_t)s * 128;
          // cache layout [cos(64)|sin(64)], cos[d]=cos[d%32], sin same
          float cv0 = rp[l15], cv1 = rp[l15 + 16];
          float sv0 = rp[64 + l15], sv1 = rp[64 + l15 + 16];
          float v0 = acc[0][0][r], v1 = acc[0][1][r];
          float v2 = acc[0][2][r], v3 = acc[0][3][r];
          if (m) { v0 = acc[1][0][r]; v1 = acc[1][1][r]; v2 = acc[1][2][r]; v3 = acc[1][3][r]; }
          v0 += bv[0]; v1 += bv[1]; v2 += bv[2]; v3 += bv[3];
          u16* po = Obf + (size_t)s * 5120 + c0;
          po[0]  = f2bf((v0 * cv0 - v2 * sv0) * scale);
          po[16] = f2bf((v1 * cv1 - v3 * sv1) * scale);
          po[32] = f2bf((v2 * cv0 + v0 * sv0) * scale);
          po[48] = f2bf((v3 * cv1 + v1 * sv1) * scale);
        }
      }
    } else {  // V: plain bias + cast
#pragma unroll
      for (int m = 0; m < 2; m++)
#pragma unroll
        for (int r = 0; r < 4; r++) {
          int s = r0 + m * 16 + r;
          u16* po = Obf + (size_t)s * 5120 + c0;
#pragma unroll
          for (int n = 0; n < 4; n++) po[n * 16] = f2bf(acc[m][n][r] + bv[n]);
        }
    }
  }
}

// ---- V transpose: src [S][ld] bf16 (cols col0+) -> dst [Hkv][64][S] bf16
__global__ __launch_bounds__(256) void cast_trT(const u16* __restrict__ src,
                                                u16* __restrict__ dst, int S, int Hkv,
                                                int ld, int col0) {
  __shared__ u16 tile[64][65];
  int s0 = blockIdx.x * 64;
  int hkv = blockIdx.y;
  int t = threadIdx.x;
  int dl = (t & 15) * 4;
  int sl = t >> 4;
#pragma unroll
  for (int j = 0; j < 4; j++) {
    int s = sl + j * 16;
    u16x4 v = *(const u16x4*)(src + (size_t)(s0 + s) * ld + col0 + hkv * 64 + dl);
    tile[dl + 0][s] = v[0];
    tile[dl + 1][s] = v[1];
    tile[dl + 2][s] = v[2];
    tile[dl + 3][s] = v[3];
  }
  __syncthreads();
  int sl2 = (t & 7) * 8;
  int dl2 = t >> 3;
#pragma unroll
  for (int j = 0; j < 2; j++) {
    int d = dl2 + j * 32;
    u16x8 o;
#pragma unroll
    for (int c = 0; c < 8; c++) o[c] = tile[d][sl2 + c];
    *(u16x8*)(dst + ((size_t)hkv * 64 + d) * S + s0 + sl2) = o;
  }
}

// ---- flash attention fwd: block = (128 q-rows, 1 head), 8 waves x 16 rows.
// Q/K read from fused qkv buffer [S][5120] (Q cols 0+, K cols 4096+).
// Swapped QK^T; log2-domain softmax; defer-max; cvt_pk P-pack.
// KV tiles of 64, counted-vmcnt 2-deep pipeline, XOR-swizzled LDS.
__global__ __launch_bounds__(512) void attn_fwd(const u16* __restrict__ QKV,
                                                const u16* __restrict__ VT,
                                                const float* __restrict__ sinks,
                                                u16* __restrict__ Out,
                                                int S, int H, int Hkv) {
  __shared__ u16 ldsK[2][64 * 64];
  __shared__ u16 ldsV[2][64 * 64];  // V^T tile: [d][k]
  __shared__ u16 ldsP[8][16 * 64];
  int qb = gridDim.x - 1 - blockIdx.x;  // long blocks first
  int h = blockIdx.y;
  int hkv = h / (H / Hkv);
  int t = threadIdx.x, lane = t & 63, wv = t >> 6;
  int l15 = lane & 15, hi = lane >> 4;
  int q0 = qb * 128 + wv * 16;
  const u16* Qh = QKV + (size_t)q0 * 5120 + h * 64;
  const u16* Kh = QKV + 4096 + hkv * 64;
  const u16* VTh = VT + (size_t)hkv * 64 * S;
  u16* ldsPw = &ldsP[wv][0];
  int psw = (l15 & 7) << 4;  // P swizzle for this lane's row

  bf16x8 qf[2];
  qf[0] = *(const bf16x8*)(Qh + (size_t)l15 * 5120 + hi * 8);
  qf[1] = *(const bf16x8*)(Qh + (size_t)l15 * 5120 + 32 + hi * 8);

  float mx = -1e30f, ls = 0.f;  // per-lane state for q-row (q0 + l15), log2 units
  f32x4 ao[4] = {};

  auto stage = [&](int b, int kb) {  // 2 loads / thread
    int k0 = kb * 64;
    int row = t >> 3, c16 = t & 7;
    int sc = (c16 ^ (row & 7)) * 8;
    gload_lds16(Kh + (size_t)(k0 + row) * 5120 + sc, &ldsK[b][t * 8]);
    gload_lds16(VTh + (size_t)row * S + k0 + sc, &ldsV[b][t * 8]);
  };

  int rowq = q0 + l15;
  int nkb = 2 * qb + 2;
  stage(0, 0);
  stage(1, 1);
  for (int kb = 0; kb < nkb; kb++) {
    int cur = kb & 1;
    if (kb + 1 < nkb) vm_wait2(); else vm_wait0();  // tile kb complete
    __builtin_amdgcn_s_barrier();
    __builtin_amdgcn_sched_barrier(0);
    if (kb * 64 <= q0 + 15) {  // wave-uniform: any unmasked cols in tile?
      // QK^T swapped: s[ct][r] = score(q = q0+l15, k = kb*64 + ct*16 + hi*4 + r)
      f32x4 s[4] = {};
      __builtin_amdgcn_s_setprio(1);
#pragma unroll
      for (int kk = 0; kk < 2; kk++) {
#pragma unroll
        for (int ct = 0; ct < 4; ct++) {
          int row = ct * 16 + l15;
          int c16 = (kk * 4 + hi) ^ (row & 7);
          bf16x8 kf = *(const bf16x8*)(&ldsK[cur][row * 64 + c16 * 8]);
          s[ct] = mfma16(kf, qf[kk], s[ct]);
        }
      }
      __builtin_amdgcn_s_setprio(0);

      bool full = (kb * 64 + 63) < q0;  // wave-uniform: whole tile unmasked
      if (!full) {
        int kc = kb * 64 + hi * 4;
#pragma unroll
        for (int ct = 0; ct < 4; ct++)
#pragma unroll
          for (int r = 0; r < 4; r++)
            if (kc + ct * 16 + r > rowq) s[ct][r] = -1e30f;
      }

      // row max: in-register tree + 2 shuffles across the 4 hi-replicas
      f32x4 mm = fmax4(fmax4(s[0], s[1]), fmax4(s[2], s[3]));
      float tmx = fmaxf(fmaxf(mm[0], mm[1]), fmaxf(mm[2], mm[3]));
      tmx = fmaxf(tmx, __shfl_xor(tmx, 16));
      tmx = fmaxf(tmx, __shfl_xor(tmx, 32));
      bool upd = __any(tmx > mx + 8.0f);  // defer-max
      if (upd) {
        float mn = fmaxf(mx, tmx);
        float al = ex2(mx - mn);
        mx = mn;
        ls *= al;
        float alr[4];
#pragma unroll
        for (int r = 0; r < 4; r++) alr[r] = __shfl(al, hi * 4 + r);
#pragma unroll
        for (int nt = 0; nt < 4; nt++)
#pragma unroll
          for (int r = 0; r < 4; r++) ao[nt][r] *= alr[r];
      }
#pragma unroll
      for (int ct = 0; ct < 4; ct++)
#pragma unroll
        for (int r = 0; r < 4; r++) s[ct][r] = ex2(s[ct][r] - mx);
      f32x4 sm = s[0] + s[1] + s[2] + s[3];
      float rs = (sm[0] + sm[1]) + (sm[2] + sm[3]);
      rs += __shfl_xor(rs, 16);
      rs += __shfl_xor(rs, 32);
      ls += rs;

      // P -> per-wave LDS (row l15, k-chunk ct*16+hi*4, XOR-swizzled, 8B writes)
#pragma unroll
      for (int ct = 0; ct < 4; ct++) {
        u32x2 pk = {cvt_pk_bf16(s[ct][0], s[ct][1]), cvt_pk_bf16(s[ct][2], s[ct][3])};
        *(u32x2*)(&ldsPw[(l15 * 128 + ((ct * 32 + hi * 8) ^ psw)) >> 1]) = pk;
      }

      // PV (per-wave ldsP: no barrier, same-wave DS ordering)
      __builtin_amdgcn_s_setprio(1);
#pragma unroll
      for (int kk = 0; kk < 2; kk++) {
        bf16x8 pa = *(const bf16x8*)(&ldsPw[(l15 * 128 + ((kk * 64 + hi * 16) ^ psw)) >> 1]);
#pragma unroll
        for (int nt = 0; nt < 4; nt++) {
          int vrow = nt * 16 + l15;
          int c16 = (kk * 4 + hi) ^ (vrow & 7);
          bf16x8 vf = *(const bf16x8*)(&ldsV[cur][vrow * 64 + c16 * 8]);
          ao[nt] = mfma16(pa, vf, ao[nt]);
        }
      }
      __builtin_amdgcn_s_setprio(0);
    }
    __builtin_amdgcn_s_barrier();          // all waves done with buf cur
    if (kb + 2 < nkb) stage(cur, kb + 2);  // refill freed buffer
  }

  float snk = sinks[h];
  float lse = 0.69314718056f * mx + __logf(ls);  // back to natural log
  float ss = 1.f / (1.f + __expf(snk - lse));
  float f = ss / ls;
  float fr[4];
#pragma unroll
  for (int r = 0; r < 4; r++) fr[r] = __shfl(f, hi * 4 + r);
#pragma unroll
  for (int r = 0; r < 4; r++) {
    int row = q0 + hi * 4 + r;
#pragma unroll
    for (int nt = 0; nt < 4; nt++)
      Out[(size_t)row * (H * 64) + h * 64 + nt * 16 + l15] = f2bf(ao[nt][r] * fr[r]);
  }
}

extern "C" void kernel_launch(void* const* d_in, const int* in_sizes, int n_in,
                              void* d_out, int out_size, void* d_ws, size_t ws_size,
                              hipStream_t stream) {
  const int S = 1536, HID = 2880, H = 64, HKV = 8;
  const int NQ = 4096, NKV = 512, NQKV = 5120, NPAD = 3072;

  const float* x     = (const float*)d_in[0];
  const float* rope  = (const float*)d_in[1];
  const float* wq_w  = (const float*)d_in[2];
  const float* wq_b  = (const float*)d_in[3];
  const float* wk_w  = (const float*)d_in[4];
  const float* wk_b  = (const float*)d_in[5];
  const float* wv_w  = (const float*)d_in[6];
  const float* wv_b  = (const float*)d_in[7];
  const float* wo_w  = (const float*)d_in[8];
  const float* wo_b  = (const float*)d_in[9];
  const float* sinks = (const float*)d_in[10];
  float* out = (float*)d_out;

  char* ws = (char*)d_ws;
  size_t off = 0;
  auto alloc = [&](size_t bytes) {
    char* p = ws + off;
    off = (off + bytes + 255) & ~(size_t)255;
    return p;
  };
  u16*   x_bf    = (u16*)  alloc((size_t)S * HID * 2);
  u16*   wqkv_bf = (u16*)  alloc((size_t)NQKV * HID * 2);
  u16*   wo_bf   = (u16*)  alloc((size_t)NPAD * NQ * 2);
  u16*   qkv_bf  = (u16*)  alloc((size_t)S * NQKV * 2);
  float* bias_p  = (float*)alloc((size_t)NQKV * 4);
  u16*   VTb     = (u16*)  alloc((size_t)HKV * 64 * S * 2);
  u16*   att     = (u16*)  alloc((size_t)S * NQ * 2);
  (void)ws_size; (void)n_in; (void)in_sizes; (void)out_size;

  auto cdiv = [](int a, int b) { return (a + b - 1) / b; };

  const int NCVT = S * HID / 4 + NQ * HID / 4 + 2 * (NKV * HID / 4) +
                   NPAD * NQ / 4 + NQKV / 4;
  cvt_all<<<cdiv(NCVT, 256), 256, 0, stream>>>(x, wq_w, wk_w, wv_w, wo_w,
                                               wq_b, wk_b, wv_b,
                                               x_bf, wqkv_bf, wo_bf, bias_p);

  // QKV projection + bias + RoPE + bf16 epilogue: grid 12 * 40 = 480 (%8==0)
  gemm128<1><<<(S / 128) * (NQKV / 128), 512, 0, stream>>>(
      x_bf, wqkv_bf, bias_p, nullptr, qkv_bf, rope, S, HID, NQKV, NQKV);

  cast_trT<<<dim3(S / 64, HKV), 256, 0, stream>>>(qkv_bf, VTb, S, HKV, NQKV, NQ + NKV);

  attn_fwd<<<dim3(S / 128, H), 512, 0, stream>>>(qkv_bf, VTb, sinks, att, S, H, HKV);

  // wo projection: grid 12 * 24 = 288 (%8==0)
  gemm128<0><<<(S / 128) * (NPAD / 128), 512, 0, stream>>>(
      att, wo_bf, wo_b, out, nullptr, nullptr, S, NQ, HID, HID);
}

// Round 12
// 201.590 us; speedup vs baseline: 2.7060x; 1.0075x over previous
//
#include <hip/hip_runtime.h>

typedef unsigned short u16;
typedef unsigned int u32;
typedef __attribute__((ext_vector_type(8))) __bf16 bf16x8;
typedef __attribute__((ext_vector_type(8))) u16 u16x8;
typedef __attribute__((ext_vector_type(4))) u16 u16x4;
typedef __attribute__((ext_vector_type(4))) float f32x4;
typedef __attribute__((ext_vector_type(2))) u32 u32x2;

#define DEV static __device__ __forceinline__

DEV u16 f2bf(float f) {
  unsigned u = __builtin_bit_cast(unsigned, f);
  u += 0x7FFFu + ((u >> 16) & 1u);
  return (u16)(u >> 16);
}

DEV float ex2(float x) { return __builtin_amdgcn_exp2f(x); }

DEV u32 cvt_pk_bf16(float lo, float hi) {
  u32 r;
  asm("v_cvt_pk_bf16_f32 %0, %1, %2" : "=v"(r) : "v"(lo), "v"(hi));
  return r;
}

DEV f32x4 mfma16(bf16x8 a, bf16x8 b, f32x4 c) {
  return __builtin_amdgcn_mfma_f32_16x16x32_bf16(a, b, c, 0, 0, 0);
}

DEV f32x4 fmax4(f32x4 a, f32x4 b) {
  f32x4 r;
  r[0] = fmaxf(a[0], b[0]); r[1] = fmaxf(a[1], b[1]);
  r[2] = fmaxf(a[2], b[2]); r[3] = fmaxf(a[3], b[3]);
  return r;
}

DEV void gload_lds16(const u16* g, u16* lds) {
  __builtin_amdgcn_global_load_lds(
      (const __attribute__((address_space(1))) void*)g,
      (__attribute__((address_space(3))) void*)lds, 16, 0, 0);
}

DEV void vm_wait4() { asm volatile("s_waitcnt vmcnt(4)" ::: "memory"); }
DEV void vm_wait0() { asm volatile("s_waitcnt vmcnt(0)" ::: "memory"); }

// ---- one-shot convert: x, wq, wk, wv -> bf16; wo -> bf16 padded; bias pack
__global__ __launch_bounds__(256) void cvt_all(
    const float* __restrict__ x, const float* __restrict__ wq,
    const float* __restrict__ wk, const float* __restrict__ wv,
    const float* __restrict__ wo, const float* __restrict__ qb,
    const float* __restrict__ kb, const float* __restrict__ vb,
    u16* __restrict__ x_bf, u16* __restrict__ wqkv_bf,
    u16* __restrict__ wo_bf, float* __restrict__ bias_p) {
  const int NX = 1536 * 2880 / 4;        // x quads
  const int NWQ = 4096 * 2880 / 4;       // wq quads
  const int NWKV = 512 * 2880 / 4;       // wk / wv quads
  const int NWO = 3072 * 4096 / 4;       // wo padded quads
  const int C0 = NX, C1 = C0 + NWQ, C2 = C1 + NWKV, C3 = C2 + NWKV;
  const int C4 = C3 + NWO, C5 = C4 + 5120 / 4;
  int i = blockIdx.x * 256 + threadIdx.x;
  if (i >= C5) return;
  if (i < C4) {
    const float* s;
    u16* d;
    bool pad = false;
    if (i < C0) { s = x + (size_t)i * 4; d = x_bf + (size_t)i * 4; }
    else if (i < C1) { size_t q = i - C0; s = wq + q * 4; d = wqkv_bf + q * 4; }
    else if (i < C2) { size_t q = i - C1; s = wk + q * 4; d = wqkv_bf + (size_t)NWQ * 4 + q * 4; }
    else if (i < C3) { size_t q = i - C2; s = wv + q * 4; d = wqkv_bf + (size_t)(NWQ + NWKV) * 4 + q * 4; }
    else {
      size_t q = i - C3;
      int row = (int)(q >> 10);  // 4096/4 = 1024 quads per row
      pad = (row >= 2880);
      s = wo + q * 4; d = wo_bf + q * 4;
    }
    u16x4 o;
    if (!pad) {
      float4 v = *(const float4*)s;
      o = (u16x4){f2bf(v.x), f2bf(v.y), f2bf(v.z), f2bf(v.w)};
    } else {
      o = (u16x4){0, 0, 0, 0};
    }
    *(u16x4*)d = o;
  } else {
    int e = (i - C4) * 4;
#pragma unroll
    for (int j = 0; j < 4; j++) {
      int idx = e + j;
      bias_p[idx] = (idx < 4096) ? qb[idx] : (idx < 4608 ? kb[idx - 4096] : vb[idx - 4608]);
    }
  }
}

// ---- 128x128 tile GEMM, BK=64, 8 waves (4x2), counted-vmcnt 2-deep pipeline,
// XOR-swizzled LDS, bm-inner XCD-chunked order. grid %8 == 0.
// MODE 0: C fp32 = A*B^T + bias (cols < Nreal).
// MODE 1: QKV epilogue -> Obf[S][5120] bf16 with bias + RoPE(Q,K) + Q-scale.
template <int MODE>
__global__ __launch_bounds__(512) void gemm128(const u16* __restrict__ A,
                                               const u16* __restrict__ B,
                                               const float* __restrict__ bias,
                                               float* __restrict__ C,
                                               u16* __restrict__ Obf,
                                               const float* __restrict__ rope,
                                               int M, int K, int Nreal, int ldc) {
  __shared__ u16 smA[2][128 * 64];
  __shared__ u16 smB[2][128 * 64];
  int nbm = M >> 7;
  int chunk = gridDim.x >> 3;
  int wg = (blockIdx.x & 7) * chunk + (blockIdx.x >> 3);
  int bm = wg % nbm, bn = wg / nbm;
  int t = threadIdx.x, lane = t & 63, wv = t >> 6;
  int wr = wv >> 1, wc = wv & 1;  // 4x2 wave grid; wave tile 32 rows x 64 cols
  int l15 = lane & 15, hi = lane >> 4;
  f32x4 acc[2][4] = {};
  int tr = t >> 3;
  int scol = ((t & 7) ^ (tr & 7)) * 8;
  const u16* Ab = A + (size_t)(bm * 128 + tr) * K + scol;
  const u16* Bb = B + (size_t)(bn * 128 + tr) * K + scol;

  auto stage = [&](int b, int ks) {  // 4 loads / thread
    int k0 = ks * 64;
    gload_lds16(Ab + k0, &smA[b][t * 8]);
    gload_lds16(Ab + k0 + (size_t)64 * K, &smA[b][4096 + t * 8]);
    gload_lds16(Bb + k0, &smB[b][t * 8]);
    gload_lds16(Bb + k0 + (size_t)64 * K, &smB[b][4096 + t * 8]);
  };

  int NK = K >> 6;
  stage(0, 0);
  stage(1, 1);
  for (int ks = 0; ks < NK; ks++) {
    int cur = ks & 1;
    if (ks + 1 < NK) vm_wait4(); else vm_wait0();  // tile ks complete
    __builtin_amdgcn_s_barrier();
    __builtin_amdgcn_sched_barrier(0);
#pragma unroll
    for (int kk = 0; kk < 2; kk++) {
      int sc = ((kk * 4 + hi) ^ (l15 & 7)) * 8;
      bf16x8 af[2], bfr[4];
#pragma unroll
      for (int m = 0; m < 2; m++)
        af[m] = *(const bf16x8*)(&smA[cur][(wr * 32 + m * 16 + l15) * 64 + sc]);
#pragma unroll
      for (int n = 0; n < 4; n++)
        bfr[n] = *(const bf16x8*)(&smB[cur][(wc * 64 + n * 16 + l15) * 64 + sc]);
      __builtin_amdgcn_s_setprio(1);
#pragma unroll
      for (int m = 0; m < 2; m++)
#pragma unroll
        for (int n = 0; n < 4; n++)
          acc[m][n] = mfma16(af[m], bfr[n], acc[m][n]);
      __builtin_amdgcn_s_setprio(0);
    }
    __builtin_amdgcn_s_barrier();        // all waves done reading buf cur
    if (ks + 2 < NK) stage(cur, ks + 2); // refill freed buffer
  }

  int r0 = bm * 128 + wr * 32 + hi * 4;
  int c0 = bn * 128 + wc * 64 + l15;
  if (MODE == 0) {
#pragma unroll
    for (int n = 0; n < 4; n++) {
      int col = c0 + n * 16;
      if (col >= Nreal) continue;
      float bv = bias[col];
#pragma unroll
      for (int m = 0; m < 2; m++)
#pragma unroll
        for (int r = 0; r < 4; r++)
          C[(size_t)(r0 + m * 16 + r) * ldc + col] = acc[m][n][r] + bv;
    }
  } else {
    float bv[4];
#pragma unroll
    for (int n = 0; n < 4; n++) bv[n] = bias[c0 + n * 16];
    if (bn < 36) {  // Q or K head: RoPE (head = 64 cols = one wave tile)
      float scale = (bn < 32) ? 0.180336880f : 1.0f;  // Q: 0.125*log2(e)
#pragma unroll
      for (int m = 0; m < 2; m++) {
#pragma unroll
        for (int r = 0; r < 4; r++) {
          int s = r0 + m * 16 + r;
          const float* rp = rope + (size_t)s * 128;
          float cv0 = rp[l15], cv1 = rp[l15 + 16];
          float sv0 = rp[64 + l15], sv1 = rp[64 + l15 + 16];
          float v0 = acc[0][0][r], v1 = acc[0][1][r];
          float v2 = acc[0][2][r], v3 = acc[0][3][r];
          if (m) { v0 = acc[1][0][r]; v1 = acc[1][1][r]; v2 = acc[1][2][r]; v3 = acc[1][3][r]; }
          v0 += bv[0]; v1 += bv[1]; v2 += bv[2]; v3 += bv[3];
          u16* po = Obf + (size_t)s * 5120 + c0;
          po[0]  = f2bf((v0 * cv0 - v2 * sv0) * scale);
          po[16] = f2bf((v1 * cv1 - v3 * sv1) * scale);
          po[32] = f2bf((v2 * cv0 + v0 * sv0) * scale);
          po[48] = f2bf((v3 * cv1 + v1 * sv1) * scale);
        }
      }
    } else {  // V: plain bias + cast
#pragma unroll
      for (int m = 0; m < 2; m++)
#pragma unroll
        for (int r = 0; r < 4; r++) {
          int s = r0 + m * 16 + r;
          u16* po = Obf + (size_t)s * 5120 + c0;
#pragma unroll
          for (int n = 0; n < 4; n++) po[n * 16] = f2bf(acc[m][n][r] + bv[n]);
        }
    }
  }
}

// ---- V transpose: src [S][ld] bf16 (cols col0+) -> dst [Hkv][64][S] bf16
__global__ __launch_bounds__(256) void cast_trT(const u16* __restrict__ src,
                                                u16* __restrict__ dst, int S, int Hkv,
                                                int ld, int col0) {
  __shared__ u16 tile[64][65];
  int s0 = blockIdx.x * 64;
  int hkv = blockIdx.y;
  int t = threadIdx.x;
  int dl = (t & 15) * 4;
  int sl = t >> 4;
#pragma unroll
  for (int j = 0; j < 4; j++) {
    int s = sl + j * 16;
    u16x4 v = *(const u16x4*)(src + (size_t)(s0 + s) * ld + col0 + hkv * 64 + dl);
    tile[dl + 0][s] = v[0];
    tile[dl + 1][s] = v[1];
    tile[dl + 2][s] = v[2];
    tile[dl + 3][s] = v[3];
  }
  __syncthreads();
  int sl2 = (t & 7) * 8;
  int dl2 = t >> 3;
#pragma unroll
  for (int j = 0; j < 2; j++) {
    int d = dl2 + j * 32;
    u16x8 o;
#pragma unroll
    for (int c = 0; c < 8; c++) o[c] = tile[d][sl2 + c];
    *(u16x8*)(dst + ((size_t)hkv * 64 + d) * S + s0 + sl2) = o;
  }
}

// ---- flash attention fwd: block = (64 q-rows, 1 head), 4 waves x 16 rows.
// Round-8 kernel with 64-row tiles: grid 24x64 = 1536 blocks at 40KB LDS
// (4 blocks/CU = 1024 slots) -> scheduler backfill balances causal skew.
// Reversed order: long blocks first. Round-8 two-barrier counted-vmcnt
// skeleton; stage loop = round-3-verified 256-thread form (4 loads/thread).
__global__ __launch_bounds__(256) void attn_fwd(const u16* __restrict__ QKV,
                                                const u16* __restrict__ VT,
                                                const float* __restrict__ sinks,
                                                u16* __restrict__ Out,
                                                int S, int H, int Hkv) {
  __shared__ u16 ldsK[2][64 * 64];
  __shared__ u16 ldsV[2][64 * 64];  // V^T tile: [d][k]
  __shared__ u16 ldsP[4][16 * 64];
  int qb = gridDim.x - 1 - blockIdx.x;  // long blocks first
  int h = blockIdx.y;
  int hkv = h / (H / Hkv);
  int t = threadIdx.x, lane = t & 63, wv = t >> 6;
  int l15 = lane & 15, hi = lane >> 4;
  int q0 = qb * 64 + wv * 16;
  const u16* Qh = QKV + (size_t)q0 * 5120 + h * 64;
  const u16* Kh = QKV + 4096 + hkv * 64;
  const u16* VTh = VT + (size_t)hkv * 64 * S;
  u16* ldsPw = &ldsP[wv][0];
  int psw = (l15 & 7) << 4;  // P swizzle for this lane's row

  bf16x8 qf[2];
  qf[0] = *(const bf16x8*)(Qh + (size_t)l15 * 5120 + hi * 8);
  qf[1] = *(const bf16x8*)(Qh + (size_t)l15 * 5120 + 32 + hi * 8);

  float mx = -1e30f, ls = 0.f;  // per-lane state for q-row (q0 + l15), log2 units
  f32x4 ao[4] = {};

  auto stage = [&](int b, int kb) {  // 4 loads / thread: full 64x64 tiles
    int k0 = kb * 64;
#pragma unroll
    for (int i = 0; i < 2; i++) {
      int c = i * 256 + t;
      int row = c >> 3, c16 = c & 7;
      int sc = (c16 ^ (row & 7)) * 8;
      gload_lds16(Kh + (size_t)(k0 + row) * 5120 + sc, &ldsK[b][c * 8]);
      gload_lds16(VTh + (size_t)row * S + k0 + sc, &ldsV[b][c * 8]);
    }
  };

  int rowq = q0 + l15;
  int nkb = qb + 1;
  stage(0, 0);
  if (nkb > 1) stage(1, 1);
  for (int kb = 0; kb < nkb; kb++) {
    int cur = kb & 1;
    if (kb + 1 < nkb) vm_wait4(); else vm_wait0();  // tile kb complete
    __builtin_amdgcn_s_barrier();
    __builtin_amdgcn_sched_barrier(0);
    {
      // QK^T swapped: s[ct][r] = score(q = q0+l15, k = kb*64 + ct*16 + hi*4 + r)
      f32x4 s[4] = {};
      __builtin_amdgcn_s_setprio(1);
#pragma unroll
      for (int kk = 0; kk < 2; kk++) {
#pragma unroll
        for (int ct = 0; ct < 4; ct++) {
          int row = ct * 16 + l15;
          int c16 = (kk * 4 + hi) ^ (row & 7);
          bf16x8 kf = *(const bf16x8*)(&ldsK[cur][row * 64 + c16 * 8]);
          s[ct] = mfma16(kf, qf[kk], s[ct]);
        }
      }
      __builtin_amdgcn_s_setprio(0);

      bool full = (kb * 64 + 63) < q0;  // wave-uniform: whole tile unmasked
      if (!full) {
        int kc = kb * 64 + hi * 4;
#pragma unroll
        for (int ct = 0; ct < 4; ct++)
#pragma unroll
          for (int r = 0; r < 4; r++)
            if (kc + ct * 16 + r > rowq) s[ct][r] = -1e30f;
      }

      // row max: in-register tree + 2 shuffles across the 4 hi-replicas
      f32x4 mm = fmax4(fmax4(s[0], s[1]), fmax4(s[2], s[3]));
      float tmx = fmaxf(fmaxf(mm[0], mm[1]), fmaxf(mm[2], mm[3]));
      tmx = fmaxf(tmx, __shfl_xor(tmx, 16));
      tmx = fmaxf(tmx, __shfl_xor(tmx, 32));
      bool upd = __any(tmx > mx + 8.0f);  // defer-max
      if (upd) {
        float mn = fmaxf(mx, tmx);
        float al = ex2(mx - mn);
        mx = mn;
        ls *= al;
        float alr[4];
#pragma unroll
        for (int r = 0; r < 4; r++) alr[r] = __shfl(al, hi * 4 + r);
#pragma unroll
        for (int nt = 0; nt < 4; nt++)
#pragma unroll
          for (int r = 0; r < 4; r++) ao[nt][r] *= alr[r];
      }
#pragma unroll
      for (int ct = 0; ct < 4; ct++)
#pragma unroll
        for (int r = 0; r < 4; r++) s[ct][r] = ex2(s[ct][r] - mx);
      f32x4 sm = s[0] + s[1] + s[2] + s[3];
      float rs = (sm[0] + sm[1]) + (sm[2] + sm[3]);
      rs += __shfl_xor(rs, 16);
      rs += __shfl_xor(rs, 32);
      ls += rs;

      // P -> per-wave LDS (row l15, k-chunk ct*16+hi*4, XOR-swizzled, 8B writes)
#pragma unroll
      for (int ct = 0; ct < 4; ct++) {
        u32x2 pk = {cvt_pk_bf16(s[ct][0], s[ct][1]), cvt_pk_bf16(s[ct][2], s[ct][3])};
        *(u32x2*)(&ldsPw[(l15 * 128 + ((ct * 32 + hi * 8) ^ psw)) >> 1]) = pk;
      }

      // PV (per-wave ldsP: no barrier, same-wave DS ordering)
      __builtin_amdgcn_s_setprio(1);
#pragma unroll
      for (int kk = 0; kk < 2; kk++) {
        bf16x8 pa = *(const bf16x8*)(&ldsPw[(l15 * 128 + ((kk * 64 + hi * 16) ^ psw)) >> 1]);
#pragma unroll
        for (int nt = 0; nt < 4; nt++) {
          int vrow = nt * 16 + l15;
          int c16 = (kk * 4 + hi) ^ (vrow & 7);
          bf16x8 vf = *(const bf16x8*)(&ldsV[cur][vrow * 64 + c16 * 8]);
          ao[nt] = mfma16(pa, vf, ao[nt]);
        }
      }
      __builtin_amdgcn_s_setprio(0);
    }
    __builtin_amdgcn_s_barrier();          // all waves done with buf cur
    if (kb + 2 < nkb) stage(cur, kb + 2);  // refill freed buffer
  }

  float snk = sinks[h];
  float lse = 0.69314718056f * mx + __logf(ls);  // back to natural log
  float ss = 1.f / (1.f + __expf(snk - lse));
  float f = ss / ls;
  float fr[4];
#pragma unroll
  for (int r = 0; r < 4; r++) fr[r] = __shfl(f, hi * 4 + r);
#pragma unroll
  for (int r = 0; r < 4; r++) {
    int row = q0 + hi * 4 + r;
#pragma unroll
    for (int nt = 0; nt < 4; nt++)
      Out[(size_t)row * (H * 64) + h * 64 + nt * 16 + l15] = f2bf(ao[nt][r] * fr[r]);
  }
}

extern "C" void kernel_launch(void* const* d_in, const int* in_sizes, int n_in,
                              void* d_out, int out_size, void* d_ws, size_t ws_size,
                              hipStream_t stream) {
  const int S = 1536, HID = 2880, H = 64, HKV = 8;
  const int NQ = 4096, NKV = 512, NQKV = 5120, NPAD = 3072;

  const float* x     = (const float*)d_in[0];
  const float* rope  = (const float*)d_in[1];
  const float* wq_w  = (const float*)d_in[2];
  const float* wq_b  = (const float*)d_in[3];
  const float* wk_w  = (const float*)d_in[4];
  const float* wk_b  = (const float*)d_in[5];
  const float* wv_w  = (const float*)d_in[6];
  const float* wv_b  = (const float*)d_in[7];
  const float* wo_w  = (const float*)d_in[8];
  const float* wo_b  = (const float*)d_in[9];
  const float* sinks = (const float*)d_in[10];
  float* out = (float*)d_out;

  char* ws = (char*)d_ws;
  size_t off = 0;
  auto alloc = [&](size_t bytes) {
    char* p = ws + off;
    off = (off + bytes + 255) & ~(size_t)255;
    return p;
  };
  u16*   x_bf    = (u16*)  alloc((size_t)S * HID * 2);
  u16*   wqkv_bf = (u16*)  alloc((size_t)NQKV * HID * 2);
  u16*   wo_bf   = (u16*)  alloc((size_t)NPAD * NQ * 2);
  u16*   qkv_bf  = (u16*)  alloc((size_t)S * NQKV * 2);
  float* bias_p  = (float*)alloc((size_t)NQKV * 4);
  u16*   VTb     = (u16*)  alloc((size_t)HKV * 64 * S * 2);
  u16*   att     = (u16*)  alloc((size_t)S * NQ * 2);
  (void)ws_size; (void)n_in; (void)in_sizes; (void)out_size;

  auto cdiv = [](int a, int b) { return (a + b - 1) / b; };

  const int NCVT = S * HID / 4 + NQ * HID / 4 + 2 * (NKV * HID / 4) +
                   NPAD * NQ / 4 + NQKV / 4;
  cvt_all<<<cdiv(NCVT, 256), 256, 0, stream>>>(x, wq_w, wk_w, wv_w, wo_w,
                                               wq_b, wk_b, wv_b,
                                               x_bf, wqkv_bf, wo_bf, bias_p);

  // QKV projection + bias + RoPE + bf16 epilogue: grid 12 * 40 = 480 (%8==0)
  gemm128<1><<<(S / 128) * (NQKV / 128), 512, 0, stream>>>(
      x_bf, wqkv_bf, bias_p, nullptr, qkv_bf, rope, S, HID, NQKV, NQKV);

  cast_trT<<<dim3(S / 64, HKV), 256, 0, stream>>>(qkv_bf, VTb, S, HKV, NQKV, NQ + NKV);

  // 24 x 64-row q-tiles x 64 heads = 1536 blocks (4/CU -> backfill balance)
  attn_fwd<<<dim3(S / 64, H), 256, 0, stream>>>(qkv_bf, VTb, sinks, att, S, H, HKV);

  // wo projection: grid 12 * 24 = 288 (%8==0)
  gemm128<0><<<(S / 128) * (NPAD / 128), 512, 0, stream>>>(
      att, wo_bf, wo_b, out, nullptr, nullptr, S, NQ, HID, HID);
}

// Round 13
// 186.628 us; speedup vs baseline: 2.9230x; 1.0802x over previous
//
#include <hip/hip_runtime.h>

typedef unsigned short u16;
typedef unsigned int u32;
typedef __attribute__((ext_vector_type(8))) __bf16 bf16x8;
typedef __attribute__((ext_vector_type(8))) u16 u16x8;
typedef __attribute__((ext_vector_type(4))) u16 u16x4;
typedef __attribute__((ext_vector_type(4))) float f32x4;
typedef __attribute__((ext_vector_type(2))) u32 u32x2;

#define DEV static __device__ __forceinline__

DEV u16 f2bf(float f) {
  unsigned u = __builtin_bit_cast(unsigned, f);
  u += 0x7FFFu + ((u >> 16) & 1u);
  return (u16)(u >> 16);
}

DEV float ex2(float x) { return __builtin_amdgcn_exp2f(x); }

DEV u32 cvt_pk_bf16(float lo, float hi) {
  u32 r;
  asm("v_cvt_pk_bf16_f32 %0, %1, %2" : "=v"(r) : "v"(lo), "v"(hi));
  return r;
}

DEV f32x4 mfma16(bf16x8 a, bf16x8 b, f32x4 c) {
  return __builtin_amdgcn_mfma_f32_16x16x32_bf16(a, b, c, 0, 0, 0);
}

DEV f32x4 fmax4(f32x4 a, f32x4 b) {
  f32x4 r;
  r[0] = fmaxf(a[0], b[0]); r[1] = fmaxf(a[1], b[1]);
  r[2] = fmaxf(a[2], b[2]); r[3] = fmaxf(a[3], b[3]);
  return r;
}

DEV void gload_lds16(const u16* g, u16* lds) {
  __builtin_amdgcn_global_load_lds(
      (const __attribute__((address_space(1))) void*)g,
      (__attribute__((address_space(3))) void*)lds, 16, 0, 0);
}

DEV void vm_wait4() { asm volatile("s_waitcnt vmcnt(4)" ::: "memory"); }
DEV void vm_wait2() { asm volatile("s_waitcnt vmcnt(2)" ::: "memory"); }
DEV void vm_wait0() { asm volatile("s_waitcnt vmcnt(0)" ::: "memory"); }

// ---- one-shot convert: x, wq, wk, wv -> bf16; wo -> bf16 padded; bias pack
__global__ __launch_bounds__(256) void cvt_all(
    const float* __restrict__ x, const float* __restrict__ wq,
    const float* __restrict__ wk, const float* __restrict__ wv,
    const float* __restrict__ wo, const float* __restrict__ qb,
    const float* __restrict__ kb, const float* __restrict__ vb,
    u16* __restrict__ x_bf, u16* __restrict__ wqkv_bf,
    u16* __restrict__ wo_bf, float* __restrict__ bias_p) {
  const int NX = 1536 * 2880 / 4;        // x quads
  const int NWQ = 4096 * 2880 / 4;       // wq quads
  const int NWKV = 512 * 2880 / 4;       // wk / wv quads
  const int NWO = 3072 * 4096 / 4;       // wo padded quads
  const int C0 = NX, C1 = C0 + NWQ, C2 = C1 + NWKV, C3 = C2 + NWKV;
  const int C4 = C3 + NWO, C5 = C4 + 5120 / 4;
  int i = blockIdx.x * 256 + threadIdx.x;
  if (i >= C5) return;
  if (i < C4) {
    const float* s;
    u16* d;
    bool pad = false;
    if (i < C0) { s = x + (size_t)i * 4; d = x_bf + (size_t)i * 4; }
    else if (i < C1) { size_t q = i - C0; s = wq + q * 4; d = wqkv_bf + q * 4; }
    else if (i < C2) { size_t q = i - C1; s = wk + q * 4; d = wqkv_bf + (size_t)NWQ * 4 + q * 4; }
    else if (i < C3) { size_t q = i - C2; s = wv + q * 4; d = wqkv_bf + (size_t)(NWQ + NWKV) * 4 + q * 4; }
    else {
      size_t q = i - C3;
      int row = (int)(q >> 10);  // 4096/4 = 1024 quads per row
      pad = (row >= 2880);
      s = wo + q * 4; d = wo_bf + q * 4;
    }
    u16x4 o;
    if (!pad) {
      float4 v = *(const float4*)s;
      o = (u16x4){f2bf(v.x), f2bf(v.y), f2bf(v.z), f2bf(v.w)};
    } else {
      o = (u16x4){0, 0, 0, 0};
    }
    *(u16x4*)d = o;
  } else {
    int e = (i - C4) * 4;
#pragma unroll
    for (int j = 0; j < 4; j++) {
      int idx = e + j;
      bias_p[idx] = (idx < 4096) ? qb[idx] : (idx < 4608 ? kb[idx - 4096] : vb[idx - 4608]);
    }
  }
}

// ---- 128x128 tile GEMM, BK=64, 8 waves (4x2), counted-vmcnt 2-deep pipeline,
// XOR-swizzled LDS, bm-inner XCD-chunked order. grid %8 == 0.
// MODE 0: C fp32 = A*B^T + bias (cols < Nreal).
// MODE 1: QKV epilogue -> Obf[S][5120] bf16 with bias + RoPE(Q,K) + Q-scale.
template <int MODE>
__global__ __launch_bounds__(512) void gemm128(const u16* __restrict__ A,
                                               const u16* __restrict__ B,
                                               const float* __restrict__ bias,
                                               float* __restrict__ C,
                                               u16* __restrict__ Obf,
                                               const float* __restrict__ rope,
                                               int M, int K, int Nreal, int ldc) {
  __shared__ u16 smA[2][128 * 64];
  __shared__ u16 smB[2][128 * 64];
  int nbm = M >> 7;
  int chunk = gridDim.x >> 3;
  int wg = (blockIdx.x & 7) * chunk + (blockIdx.x >> 3);
  int bm = wg % nbm, bn = wg / nbm;
  int t = threadIdx.x, lane = t & 63, wv = t >> 6;
  int wr = wv >> 1, wc = wv & 1;  // 4x2 wave grid; wave tile 32 rows x 64 cols
  int l15 = lane & 15, hi = lane >> 4;
  f32x4 acc[2][4] = {};
  int tr = t >> 3;
  int scol = ((t & 7) ^ (tr & 7)) * 8;
  const u16* Ab = A + (size_t)(bm * 128 + tr) * K + scol;
  const u16* Bb = B + (size_t)(bn * 128 + tr) * K + scol;

  auto stage = [&](int b, int ks) {  // 4 loads / thread
    int k0 = ks * 64;
    gload_lds16(Ab + k0, &smA[b][t * 8]);
    gload_lds16(Ab + k0 + (size_t)64 * K, &smA[b][4096 + t * 8]);
    gload_lds16(Bb + k0, &smB[b][t * 8]);
    gload_lds16(Bb + k0 + (size_t)64 * K, &smB[b][4096 + t * 8]);
  };

  int NK = K >> 6;
  stage(0, 0);
  stage(1, 1);
  for (int ks = 0; ks < NK; ks++) {
    int cur = ks & 1;
    if (ks + 1 < NK) vm_wait4(); else vm_wait0();  // tile ks complete
    __builtin_amdgcn_s_barrier();
    __builtin_amdgcn_sched_barrier(0);
#pragma unroll
    for (int kk = 0; kk < 2; kk++) {
      int sc = ((kk * 4 + hi) ^ (l15 & 7)) * 8;
      bf16x8 af[2], bfr[4];
#pragma unroll
      for (int m = 0; m < 2; m++)
        af[m] = *(const bf16x8*)(&smA[cur][(wr * 32 + m * 16 + l15) * 64 + sc]);
#pragma unroll
      for (int n = 0; n < 4; n++)
        bfr[n] = *(const bf16x8*)(&smB[cur][(wc * 64 + n * 16 + l15) * 64 + sc]);
      __builtin_amdgcn_s_setprio(1);
#pragma unroll
      for (int m = 0; m < 2; m++)
#pragma unroll
        for (int n = 0; n < 4; n++)
          acc[m][n] = mfma16(af[m], bfr[n], acc[m][n]);
      __builtin_amdgcn_s_setprio(0);
    }
    __builtin_amdgcn_s_barrier();        // all waves done reading buf cur
    if (ks + 2 < NK) stage(cur, ks + 2); // refill freed buffer
  }

  int r0 = bm * 128 + wr * 32 + hi * 4;
  int c0 = bn * 128 + wc * 64 + l15;
  if (MODE == 0) {
#pragma unroll
    for (int n = 0; n < 4; n++) {
      int col = c0 + n * 16;
      if (col >= Nreal) continue;
      float bv = bias[col];
#pragma unroll
      for (int m = 0; m < 2; m++)
#pragma unroll
        for (int r = 0; r < 4; r++)
          C[(size_t)(r0 + m * 16 + r) * ldc + col] = acc[m][n][r] + bv;
    }
  } else {
    float bv[4];
#pragma unroll
    for (int n = 0; n < 4; n++) bv[n] = bias[c0 + n * 16];
    if (bn < 36) {  // Q or K head: RoPE (head = 64 cols = one wave tile)
      float scale = (bn < 32) ? 0.180336880f : 1.0f;  // Q: 0.125*log2(e)
#pragma unroll
      for (int m = 0; m < 2; m++) {
#pragma unroll
        for (int r = 0; r < 4; r++) {
          int s = r0 + m * 16 + r;
          const float* rp = rope + (size_t)s * 128;
          float cv0 = rp[l15], cv1 = rp[l15 + 16];
          float sv0 = rp[64 + l15], sv1 = rp[64 + l15 + 16];
          float v0 = acc[0][0][r], v1 = acc[0][1][r];
          float v2 = acc[0][2][r], v3 = acc[0][3][r];
          if (m) { v0 = acc[1][0][r]; v1 = acc[1][1][r]; v2 = acc[1][2][r]; v3 = acc[1][3][r]; }
          v0 += bv[0]; v1 += bv[1]; v2 += bv[2]; v3 += bv[3];
          u16* po = Obf + (size_t)s * 5120 + c0;
          po[0]  = f2bf((v0 * cv0 - v2 * sv0) * scale);
          po[16] = f2bf((v1 * cv1 - v3 * sv1) * scale);
          po[32] = f2bf((v2 * cv0 + v0 * sv0) * scale);
          po[48] = f2bf((v3 * cv1 + v1 * sv1) * scale);
        }
      }
    } else {  // V: plain bias + cast
#pragma unroll
      for (int m = 0; m < 2; m++)
#pragma unroll
        for (int r = 0; r < 4; r++) {
          int s = r0 + m * 16 + r;
          u16* po = Obf + (size_t)s * 5120 + c0;
#pragma unroll
          for (int n = 0; n < 4; n++) po[n * 16] = f2bf(acc[m][n][r] + bv[n]);
        }
    }
  }
}

// ---- V transpose: src [S][ld] bf16 (cols col0+) -> dst [Hkv][64][S] bf16
__global__ __launch_bounds__(256) void cast_trT(const u16* __restrict__ src,
                                                u16* __restrict__ dst, int S, int Hkv,
                                                int ld, int col0) {
  __shared__ u16 tile[64][65];
  int s0 = blockIdx.x * 64;
  int hkv = blockIdx.y;
  int t = threadIdx.x;
  int dl = (t & 15) * 4;
  int sl = t >> 4;
#pragma unroll
  for (int j = 0; j < 4; j++) {
    int s = sl + j * 16;
    u16x4 v = *(const u16x4*)(src + (size_t)(s0 + s) * ld + col0 + hkv * 64 + dl);
    tile[dl + 0][s] = v[0];
    tile[dl + 1][s] = v[1];
    tile[dl + 2][s] = v[2];
    tile[dl + 3][s] = v[3];
  }
  __syncthreads();
  int sl2 = (t & 7) * 8;
  int dl2 = t >> 3;
#pragma unroll
  for (int j = 0; j < 2; j++) {
    int d = dl2 + j * 32;
    u16x8 o;
#pragma unroll
    for (int c = 0; c < 8; c++) o[c] = tile[d][sl2 + c];
    *(u16x8*)(dst + ((size_t)hkv * 64 + d) * S + s0 + sl2) = o;
  }
}

// ---- flash attention fwd: block = 8 waves (512 thr), TWO heads sharing one
// hkv group (waves 0-3 -> head 2*pair, waves 4-7 -> head 2*pair+1; K/V tiles
// staged once, used by both), and TWO sequential q-tile passes for uniform
// work: qbA = 12+bx (long) then qbB = 11-bx (short) -> exactly 25 staged
// tiles per block, 384 blocks all uniform. Per-wave state is single (no
// interleaved dual-state). Skeleton = round-12 verified two-barrier
// counted-vmcnt pipeline (vm_wait2: 2 loads/stage).
__global__ __launch_bounds__(512) void attn_fwd(const u16* __restrict__ QKV,
                                                const u16* __restrict__ VT,
                                                const float* __restrict__ sinks,
                                                u16* __restrict__ Out,
                                                int S, int H, int Hkv) {
  __shared__ u16 ldsK[2][64 * 64];
  __shared__ u16 ldsV[2][64 * 64];  // V^T tile: [d][k]
  __shared__ u16 ldsP[8][16 * 64];
  int bx = blockIdx.x, pair = blockIdx.y;
  int t = threadIdx.x, lane = t & 63, wv = t >> 6;
  int wq = wv & 3;                // q-tile slice within pass
  int h = pair * 2 + (wv >> 2);   // this wave's head
  int hkv = pair >> 2;            // shared by both heads of the pair
  int l15 = lane & 15, hi = lane >> 4;
  const u16* Kh = QKV + 4096 + hkv * 64;
  const u16* VTh = VT + (size_t)hkv * 64 * S;
  u16* ldsPw = &ldsP[wv][0];
  int psw = (l15 & 7) << 4;  // P swizzle for this lane's row
  float snk = sinks[h];

  auto stage = [&](int b, int kb) {  // 2 loads / thread (512 thr = full tiles)
    int k0 = kb * 64;
    int row = t >> 3, c16 = t & 7;
    int sc = (c16 ^ (row & 7)) * 8;
    gload_lds16(Kh + (size_t)(k0 + row) * 5120 + sc, &ldsK[b][t * 8]);
    gload_lds16(VTh + (size_t)row * S + k0 + sc, &ldsV[b][t * 8]);
  };

  for (int pass = 0; pass < 2; pass++) {
    int qb = pass == 0 ? (12 + bx) : (11 - bx);
    int q0 = qb * 64 + wq * 16;
    int rowq = q0 + l15;
    const u16* Qh = QKV + (size_t)q0 * 5120 + h * 64;
    bf16x8 qf[2];
    qf[0] = *(const bf16x8*)(Qh + (size_t)l15 * 5120 + hi * 8);
    qf[1] = *(const bf16x8*)(Qh + (size_t)l15 * 5120 + 32 + hi * 8);

    float mx = -1e30f, ls = 0.f;  // per-lane state for q-row (q0 + l15), log2
    f32x4 ao[4] = {};

    int nkb = qb + 1;
    stage(0, 0);
    if (nkb > 1) stage(1, 1);
    for (int kb = 0; kb < nkb; kb++) {
      int cur = kb & 1;
      if (kb + 1 < nkb) vm_wait2(); else vm_wait0();  // tile kb complete
      __builtin_amdgcn_s_barrier();
      __builtin_amdgcn_sched_barrier(0);
      {
        // QK^T swapped: s[ct][r] = score(q=q0+l15, k=kb*64+ct*16+hi*4+r)
        f32x4 s[4] = {};
        __builtin_amdgcn_s_setprio(1);
#pragma unroll
        for (int kk = 0; kk < 2; kk++) {
#pragma unroll
          for (int ct = 0; ct < 4; ct++) {
            int row = ct * 16 + l15;
            int c16 = (kk * 4 + hi) ^ (row & 7);
            bf16x8 kf = *(const bf16x8*)(&ldsK[cur][row * 64 + c16 * 8]);
            s[ct] = mfma16(kf, qf[kk], s[ct]);
          }
        }
        __builtin_amdgcn_s_setprio(0);

        bool full = (kb * 64 + 63) < q0;  // wave-uniform: tile unmasked
        if (!full) {
          int kc = kb * 64 + hi * 4;
#pragma unroll
          for (int ct = 0; ct < 4; ct++)
#pragma unroll
            for (int r = 0; r < 4; r++)
              if (kc + ct * 16 + r > rowq) s[ct][r] = -1e30f;
        }

        // row max: in-register tree + 2 shuffles across the 4 hi-replicas
        f32x4 mm = fmax4(fmax4(s[0], s[1]), fmax4(s[2], s[3]));
        float tmx = fmaxf(fmaxf(mm[0], mm[1]), fmaxf(mm[2], mm[3]));
        tmx = fmaxf(tmx, __shfl_xor(tmx, 16));
        tmx = fmaxf(tmx, __shfl_xor(tmx, 32));
        bool upd = __any(tmx > mx + 8.0f);  // defer-max
        if (upd) {
          float mn = fmaxf(mx, tmx);
          float al = ex2(mx - mn);
          mx = mn;
          ls *= al;
          float alr[4];
#pragma unroll
          for (int r = 0; r < 4; r++) alr[r] = __shfl(al, hi * 4 + r);
#pragma unroll
          for (int nt = 0; nt < 4; nt++)
#pragma unroll
            for (int r = 0; r < 4; r++) ao[nt][r] *= alr[r];
        }
#pragma unroll
        for (int ct = 0; ct < 4; ct++)
#pragma unroll
          for (int r = 0; r < 4; r++) s[ct][r] = ex2(s[ct][r] - mx);
        f32x4 sm = s[0] + s[1] + s[2] + s[3];
        float rs = (sm[0] + sm[1]) + (sm[2] + sm[3]);
        rs += __shfl_xor(rs, 16);
        rs += __shfl_xor(rs, 32);
        ls += rs;

        // P -> per-wave LDS (row l15, XOR-swizzled, 8B writes)
#pragma unroll
        for (int ct = 0; ct < 4; ct++) {
          u32x2 pk = {cvt_pk_bf16(s[ct][0], s[ct][1]),
                      cvt_pk_bf16(s[ct][2], s[ct][3])};
          *(u32x2*)(&ldsPw[(l15 * 128 + ((ct * 32 + hi * 8) ^ psw)) >> 1]) = pk;
        }

        // PV (per-wave ldsP: no barrier, same-wave DS ordering)
        __builtin_amdgcn_s_setprio(1);
#pragma unroll
        for (int kk = 0; kk < 2; kk++) {
          bf16x8 pa = *(const bf16x8*)(&ldsPw[(l15 * 128 + ((kk * 64 + hi * 16) ^ psw)) >> 1]);
#pragma unroll
          for (int nt = 0; nt < 4; nt++) {
            int vrow = nt * 16 + l15;
            int c16 = (kk * 4 + hi) ^ (vrow & 7);
            bf16x8 vf = *(const bf16x8*)(&ldsV[cur][vrow * 64 + c16 * 8]);
            ao[nt] = mfma16(pa, vf, ao[nt]);
          }
        }
        __builtin_amdgcn_s_setprio(0);
      }
      __builtin_amdgcn_s_barrier();          // all waves done with buf cur
      if (kb + 2 < nkb) stage(cur, kb + 2);  // refill freed buffer
    }

    float lse = 0.69314718056f * mx + __logf(ls);  // back to natural log
    float ss = 1.f / (1.f + __expf(snk - lse));
    float f = ss / ls;
    float fr[4];
#pragma unroll
    for (int r = 0; r < 4; r++) fr[r] = __shfl(f, hi * 4 + r);
#pragma unroll
    for (int r = 0; r < 4; r++) {
      int row = q0 + hi * 4 + r;
#pragma unroll
      for (int nt = 0; nt < 4; nt++)
        Out[(size_t)row * (H * 64) + h * 64 + nt * 16 + l15] = f2bf(ao[nt][r] * fr[r]);
    }
  }
}

extern "C" void kernel_launch(void* const* d_in, const int* in_sizes, int n_in,
                              void* d_out, int out_size, void* d_ws, size_t ws_size,
                              hipStream_t stream) {
  const int S = 1536, HID = 2880, H = 64, HKV = 8;
  const int NQ = 4096, NKV = 512, NQKV = 5120, NPAD = 3072;

  const float* x     = (const float*)d_in[0];
  const float* rope  = (const float*)d_in[1];
  const float* wq_w  = (const float*)d_in[2];
  const float* wq_b  = (const float*)d_in[3];
  const float* wk_w  = (const float*)d_in[4];
  const float* wk_b  = (const float*)d_in[5];
  const float* wv_w  = (const float*)d_in[6];
  const float* wv_b  = (const float*)d_in[7];
  const float* wo_w  = (const float*)d_in[8];
  const float* wo_b  = (const float*)d_in[9];
  const float* sinks = (const float*)d_in[10];
  float* out = (float*)d_out;

  char* ws = (char*)d_ws;
  size_t off = 0;
  auto alloc = [&](size_t bytes) {
    char* p = ws + off;
    off = (off + bytes + 255) & ~(size_t)255;
    return p;
  };
  u16*   x_bf    = (u16*)  alloc((size_t)S * HID * 2);
  u16*   wqkv_bf = (u16*)  alloc((size_t)NQKV * HID * 2);
  u16*   wo_bf   = (u16*)  alloc((size_t)NPAD * NQ * 2);
  u16*   qkv_bf  = (u16*)  alloc((size_t)S * NQKV * 2);
  float* bias_p  = (float*)alloc((size_t)NQKV * 4);
  u16*   VTb     = (u16*)  alloc((size_t)HKV * 64 * S * 2);
  u16*   att     = (u16*)  alloc((size_t)S * NQ * 2);
  (void)ws_size; (void)n_in; (void)in_sizes; (void)out_size;

  auto cdiv = [](int a, int b) { return (a + b - 1) / b; };

  const int NCVT = S * HID / 4 + NQ * HID / 4 + 2 * (NKV * HID / 4) +
                   NPAD * NQ / 4 + NQKV / 4;
  cvt_all<<<cdiv(NCVT, 256), 256, 0, stream>>>(x, wq_w, wk_w, wv_w, wo_w,
                                               wq_b, wk_b, wv_b,
                                               x_bf, wqkv_bf, wo_bf, bias_p);

  // QKV projection + bias + RoPE + bf16 epilogue: grid 12 * 40 = 480 (%8==0)
  gemm128<1><<<(S / 128) * (NQKV / 128), 512, 0, stream>>>(
      x_bf, wqkv_bf, bias_p, nullptr, qkv_bf, rope, S, HID, NQKV, NQKV);

  cast_trT<<<dim3(S / 64, HKV), 256, 0, stream>>>(qkv_bf, VTb, S, HKV, NQKV, NQ + NKV);

  // 12 balanced q-pass pairs x 32 head-pairs = 384 uniform blocks
  attn_fwd<<<dim3(12, H / 2), 512, 0, stream>>>(qkv_bf, VTb, sinks, att, S, H, HKV);

  // wo projection: grid 12 * 24 = 288 (%8==0)
  gemm128<0><<<(S / 128) * (NPAD / 128), 512, 0, stream>>>(
      att, wo_bf, wo_b, out, nullptr, nullptr, S, NQ, HID, HID);
}